// Round 18
// baseline (168.522 us; speedup 1.0000x reference)
//
#include <hip/hip_runtime.h>
#include <hip/hip_fp16.h>

#define NGRAPH 256
#define FIN 64
#define HID 32
#define NB_SHIFT 8            // 256 nodes per bucket
#define NB_NODES 256
#define KMAX2 512
#define EPB 2048              // edges per partition block
#define EPT 8                 // edges per thread (256 threads)
#define NT 64                 // nodes per GEMM block
#define XPAD 65               // 64 + 1 pad (floats) per staged x row
#define HPAD 33               // 32 + 1 pad
#define PCAP 6016             // partC2 LDS edge-staging capacity

// ---------- fused: bucket_hist (blocks [0,NBLK)) + node_lin64 (rest) ----------
union SU {
    int h[KMAX2];
    struct { float Wr[FIN * HID]; float Wo[FIN * HID]; float b[HID];
             float x[NT * XPAD]; } g;
};

__global__ __launch_bounds__(256, 4) void hist_lin64(
    const int* __restrict__ dst, int* __restrict__ cbb, int E, int K, int NBLK,
    const float* __restrict__ x, const float* __restrict__ Wrel,
    const float* __restrict__ Wroot, const float* __restrict__ bias,
    __half* __restrict__ A, float* __restrict__ B, int N)
{
    __shared__ SU u;
    int tid = threadIdx.x;
    if (blockIdx.x < (unsigned)NBLK) {
        // ---- histogram role ----
        for (int i = tid; i < K; i += 256) u.h[i] = 0;
        __syncthreads();
        int e0 = blockIdx.x * EPB + tid * 8;
        if (e0 + 7 < E) {
            int4 d0 = *reinterpret_cast<const int4*>(dst + e0);
            int4 d1 = *reinterpret_cast<const int4*>(dst + e0 + 4);
            atomicAdd(&u.h[d0.x >> NB_SHIFT], 1); atomicAdd(&u.h[d0.y >> NB_SHIFT], 1);
            atomicAdd(&u.h[d0.z >> NB_SHIFT], 1); atomicAdd(&u.h[d0.w >> NB_SHIFT], 1);
            atomicAdd(&u.h[d1.x >> NB_SHIFT], 1); atomicAdd(&u.h[d1.y >> NB_SHIFT], 1);
            atomicAdd(&u.h[d1.z >> NB_SHIFT], 1); atomicAdd(&u.h[d1.w >> NB_SHIFT], 1);
        } else {
            for (int e = e0; e < E && e < e0 + 8; ++e)
                atomicAdd(&u.h[dst[e] >> NB_SHIFT], 1);
        }
        __syncthreads();
        for (int i = tid; i < K; i += 256)
            cbb[(size_t)i * NBLK + blockIdx.x] = u.h[i];
        return;
    }
    // ---- conv1 linear role ----
    {
        const float4* Wr4 = (const float4*)Wrel;
        const float4* Wo4 = (const float4*)Wroot;
        for (int i = tid; i < FIN * HID / 4; i += 256) {
            ((float4*)u.g.Wr)[i] = Wr4[i];
            ((float4*)u.g.Wo)[i] = Wo4[i];
        }
        if (tid < HID) u.g.b[tid] = bias[tid];
    }
    int base = (blockIdx.x - NBLK) * NT;
    {
        const float4* x4 = (const float4*)x;
        for (int i = tid; i < NT * 16; i += 256) {
            int row = i >> 4, c4 = i & 15;
            int n = base + row;
            float4 v = (n < N) ? x4[(size_t)n * 16 + c4]
                               : make_float4(0.f, 0.f, 0.f, 0.f);
            *(float4*)&u.g.x[row * XPAD + c4 * 4] = v;
        }
    }
    __syncthreads();

    int nl = tid >> 3;          // 0..31
    int fq = (tid & 7) * 4;     // feature quad base
    const float* xa = &u.g.x[nl * XPAD];
    const float* xb = &u.g.x[(nl + 32) * XPAD];
    float4 ar0 = make_float4(0.f,0.f,0.f,0.f), ao0 = ar0;
    float4 ar1 = ar0, ao1 = ar0;
    #pragma unroll 4
    for (int k = 0; k < FIN; ++k) {
        float4 w4 = *(const float4*)&u.g.Wr[k * HID + fq];
        float4 o4 = *(const float4*)&u.g.Wo[k * HID + fq];
        float va = xa[k], vb = xb[k];
        ar0.x = fmaf(va, w4.x, ar0.x); ar0.y = fmaf(va, w4.y, ar0.y);
        ar0.z = fmaf(va, w4.z, ar0.z); ar0.w = fmaf(va, w4.w, ar0.w);
        ao0.x = fmaf(va, o4.x, ao0.x); ao0.y = fmaf(va, o4.y, ao0.y);
        ao0.z = fmaf(va, o4.z, ao0.z); ao0.w = fmaf(va, o4.w, ao0.w);
        ar1.x = fmaf(vb, w4.x, ar1.x); ar1.y = fmaf(vb, w4.y, ar1.y);
        ar1.z = fmaf(vb, w4.z, ar1.z); ar1.w = fmaf(vb, w4.w, ar1.w);
        ao1.x = fmaf(vb, o4.x, ao1.x); ao1.y = fmaf(vb, o4.y, ao1.y);
        ao1.z = fmaf(vb, o4.z, ao1.z); ao1.w = fmaf(vb, o4.w, ao1.w);
    }
    float4 bb = *(const float4*)&u.g.b[fq];
    int n0 = base + nl, n1 = base + nl + 32;
    if (n0 < N) {
        __half2 pa = __floats2half2_rn(ar0.x, ar0.y);
        __half2 pb = __floats2half2_rn(ar0.z, ar0.w);
        uint2 pk; pk.x = *(unsigned*)&pa; pk.y = *(unsigned*)&pb;
        *(uint2*)&A[(size_t)n0 * HID + fq] = pk;
        ao0.x += bb.x; ao0.y += bb.y; ao0.z += bb.z; ao0.w += bb.w;
        *(float4*)&B[(size_t)n0 * HID + fq] = ao0;
    }
    if (n1 < N) {
        __half2 pa = __floats2half2_rn(ar1.x, ar1.y);
        __half2 pb = __floats2half2_rn(ar1.z, ar1.w);
        uint2 pk; pk.x = *(unsigned*)&pa; pk.y = *(unsigned*)&pb;
        *(uint2*)&A[(size_t)n1 * HID + fq] = pk;
        ao1.x += bb.x; ao1.y += bb.y; ao1.z += bb.z; ao1.w += bb.w;
        *(float4*)&B[(size_t)n1 * HID + fq] = ao1;
    }
}

// ---------- node GEMM 2: relu fused on load, FIN=32 ----------
__global__ __launch_bounds__(256, 4) void node_lin32(
    const float* __restrict__ Hpre, const float* __restrict__ Wrel,
    const float* __restrict__ Wroot, const float* __restrict__ bias,
    __half* __restrict__ A, float* __restrict__ C, int N)
{
    __shared__ float sWr[HID * HID];      // 4 KB
    __shared__ float sWo[HID * HID];
    __shared__ float sb[HID];
    __shared__ float sh[NT * HPAD];       // 8.4 KB
    int tid = threadIdx.x;
    {
        const float4* Wr4 = (const float4*)Wrel;
        const float4* Wo4 = (const float4*)Wroot;
        for (int i = tid; i < HID * HID / 4; i += 256) {
            ((float4*)sWr)[i] = Wr4[i];
            ((float4*)sWo)[i] = Wo4[i];
        }
        if (tid < HID) sb[tid] = bias[tid];
    }
    int base = blockIdx.x * NT;
    {
        const float4* H4 = (const float4*)Hpre;
        for (int i = tid; i < NT * 8; i += 256) {
            int row = i >> 3, c4 = i & 7;
            int n = base + row;
            float4 v = make_float4(0.f, 0.f, 0.f, 0.f);
            if (n < N) {
                v = H4[(size_t)n * 8 + c4];
                v.x = v.x > 0.f ? v.x : 0.f; v.y = v.y > 0.f ? v.y : 0.f;
                v.z = v.z > 0.f ? v.z : 0.f; v.w = v.w > 0.f ? v.w : 0.f;
            }
            *(float4*)&sh[row * HPAD + c4 * 4] = v;
        }
    }
    __syncthreads();

    int nl = tid >> 3;
    int fq = (tid & 7) * 4;
    const float* xa = &sh[nl * HPAD];
    const float* xb = &sh[(nl + 32) * HPAD];
    float4 ar0 = make_float4(0.f,0.f,0.f,0.f), ao0 = ar0;
    float4 ar1 = ar0, ao1 = ar0;
    #pragma unroll 4
    for (int k = 0; k < HID; ++k) {
        float4 w4 = *(const float4*)&sWr[k * HID + fq];
        float4 o4 = *(const float4*)&sWo[k * HID + fq];
        float va = xa[k], vb = xb[k];
        ar0.x = fmaf(va, w4.x, ar0.x); ar0.y = fmaf(va, w4.y, ar0.y);
        ar0.z = fmaf(va, w4.z, ar0.z); ar0.w = fmaf(va, w4.w, ar0.w);
        ao0.x = fmaf(va, o4.x, ao0.x); ao0.y = fmaf(va, o4.y, ao0.y);
        ao0.z = fmaf(va, o4.z, ao0.z); ao0.w = fmaf(va, o4.w, ao0.w);
        ar1.x = fmaf(vb, w4.x, ar1.x); ar1.y = fmaf(vb, w4.y, ar1.y);
        ar1.z = fmaf(vb, w4.z, ar1.z); ar1.w = fmaf(vb, w4.w, ar1.w);
        ao1.x = fmaf(vb, o4.x, ao1.x); ao1.y = fmaf(vb, o4.y, ao1.y);
        ao1.z = fmaf(vb, o4.z, ao1.z); ao1.w = fmaf(vb, o4.w, ao1.w);
    }
    float4 bb = *(const float4*)&sb[fq];
    int n0 = base + nl, n1 = base + nl + 32;
    if (n0 < N) {
        __half2 pa = __floats2half2_rn(ar0.x, ar0.y);
        __half2 pb = __floats2half2_rn(ar0.z, ar0.w);
        uint2 pk; pk.x = *(unsigned*)&pa; pk.y = *(unsigned*)&pb;
        *(uint2*)&A[(size_t)n0 * HID + fq] = pk;
        ao0.x += bb.x; ao0.y += bb.y; ao0.z += bb.z; ao0.w += bb.w;
        *(float4*)&C[(size_t)n0 * HID + fq] = ao0;
    }
    if (n1 < N) {
        __half2 pa = __floats2half2_rn(ar1.x, ar1.y);
        __half2 pb = __floats2half2_rn(ar1.z, ar1.w);
        uint2 pk; pk.x = *(unsigned*)&pa; pk.y = *(unsigned*)&pb;
        *(uint2*)&A[(size_t)n1 * HID + fq] = pk;
        ao1.x += bb.x; ao1.y += bb.y; ao1.z += bb.z; ao1.w += bb.w;
        *(float4*)&C[(size_t)n1 * HID + fq] = ao1;
    }
}

// ---------- rest of the deterministic partition build ----------

__global__ __launch_bounds__(256) void bucket_scan(
    int* __restrict__ cbb, int* __restrict__ btot, int NBLK)
{
    __shared__ int sc[256];
    size_t row = (size_t)blockIdx.x * NBLK;
    int t = threadIdx.x;
    int base = t * 4;
    int v[4]; int s = 0;
    #pragma unroll
    for (int j = 0; j < 4; ++j) { v[j] = (base + j < NBLK) ? cbb[row + base + j] : 0; s += v[j]; }
    sc[t] = s;
    __syncthreads();
    int acc = s;
    for (int off = 1; off < 256; off <<= 1) {
        int add = (t >= off) ? sc[t - off] : 0;
        __syncthreads();
        acc += add;
        sc[t] = acc;
        __syncthreads();
    }
    int run = acc - s;
    #pragma unroll
    for (int j = 0; j < 4; ++j) {
        if (base + j < NBLK) cbb[row + base + j] = run;
        run += v[j];
    }
    if (t == 255) btot[blockIdx.x] = acc;
}

__global__ __launch_bounds__(256) void btot_scan(
    const int* __restrict__ btot, int* __restrict__ bbase, int K)
{
    __shared__ int sc[256];
    int t = threadIdx.x;
    int base = t * 4;
    int v[4]; int s = 0;
    #pragma unroll
    for (int j = 0; j < 4; ++j) { v[j] = (base + j < K) ? btot[base + j] : 0; s += v[j]; }
    sc[t] = s;
    __syncthreads();
    int acc = s;
    for (int off = 1; off < 256; off <<= 1) {
        int add = (t >= off) ? sc[t - off] : 0;
        __syncthreads();
        acc += add;
        sc[t] = acc;
        __syncthreads();
    }
    int run = acc - s;
    #pragma unroll
    for (int j = 0; j < 4; ++j) {
        if (base + j < K) bbase[base + j] = run;
        run += v[j];
    }
    if (t == 255) bbase[K] = acc;
}

// partition: edges -> bucket-grouped staging; payload = {src | dloc<<17, ew}
__global__ __launch_bounds__(256) void partB(
    const int* __restrict__ src, const int* __restrict__ dst,
    const float* __restrict__ ew, const int* __restrict__ cbb,
    const int* __restrict__ bbase, int2* __restrict__ stg8,
    int E, int K, int NBLK)
{
    __shared__ int4 pay[EPB];       // 32 KB: {meta, ew, tgt, pad}
    __shared__ int h[KMAX2];
    __shared__ int lofs[KMAX2];
    __shared__ int gb[KMAX2];
    __shared__ int sc[256];
    int tid = threadIdx.x;
    for (int i = tid; i < K; i += 256) h[i] = 0;
    __syncthreads();

    int base = blockIdx.x * EPB;
    int es[EPT], ds[EPT]; float wsr[EPT];
    #pragma unroll
    for (int k = 0; k < EPT; ++k) {
        int e = base + k * 256 + tid;
        if (e < E) {
            es[k] = src[e]; ds[k] = dst[e]; wsr[k] = ew[e];
            atomicAdd(&h[ds[k] >> NB_SHIFT], 1);
        } else ds[k] = -1;
    }
    __syncthreads();

    int b0 = tid * 2;
    int v0 = (b0 < K) ? h[b0] : 0;
    int v1 = (b0 + 1 < K) ? h[b0 + 1] : 0;
    int s = v0 + v1;
    sc[tid] = s;
    __syncthreads();
    int acc = s;
    for (int off = 1; off < 256; off <<= 1) {
        int add = (tid >= off) ? sc[tid - off] : 0;
        __syncthreads();
        acc += add;
        sc[tid] = acc;
        __syncthreads();
    }
    int run = acc - s;
    if (b0 < K) lofs[b0] = run;
    if (b0 + 1 < K) lofs[b0 + 1] = run + v0;
    __syncthreads();

    for (int b = tid; b < K; b += 256) {
        gb[b] = bbase[b] + cbb[(size_t)b * NBLK + blockIdx.x];
        h[b] = lofs[b];
    }
    __syncthreads();

    #pragma unroll
    for (int k = 0; k < EPT; ++k) {
        if (ds[k] >= 0) {
            int b = ds[k] >> NB_SHIFT;
            int dloc = ds[k] & (NB_NODES - 1);
            int slot = atomicAdd(&h[b], 1);
            pay[slot] = make_int4(es[k] | (dloc << 17), __float_as_int(wsr[k]),
                                  gb[b] + slot - lofs[b], 0);
        }
    }
    __syncthreads();

    int tot = E - base; if (tot > EPB) tot = EPB;
    for (int i = tid; i < tot; i += 256) {
        int4 p = pay[i];
        stg8[p.z] = make_int2(p.x, p.y);
    }
}

// per bucket: counting-sort edges by dst node (LDS-staged) -> rowptr + perm,
// then degree-sort the bucket's nodes -> norder (for divergence-free agg waves)
__global__ __launch_bounds__(512) void partC2(
    const int2* __restrict__ stg8, const int* __restrict__ bbase,
    int* __restrict__ rowptr, int2* __restrict__ perm,
    int* __restrict__ norder, int N, int K)
{
    __shared__ int2 pe[PCAP];          // 47 KB edge staging
    __shared__ int hcnt[NB_NODES];
    __shared__ int hinc[NB_NODES];
    __shared__ int dh[64];
    __shared__ int dof[64];
    int b = blockIdx.x;
    int n0 = b << NB_SHIFT;
    int nTop = n0 + NB_NODES; if (nTop > N) nTop = N;
    int nloc = nTop - n0;
    int tid = threadIdx.x;
    if (tid < NB_NODES) hcnt[tid] = 0;
    if (tid >= NB_NODES && tid < NB_NODES + 64) dh[tid - NB_NODES] = 0;
    int lo = bbase[b], hi = bbase[b + 1];
    int sz = hi - lo;
    bool fit = (sz <= PCAP);
    if (fit) {
        for (int i = tid; i < sz; i += 512) pe[i] = stg8[lo + i];
    }
    __syncthreads();
    if (fit) {
        for (int i = tid; i < sz; i += 512)
            atomicAdd(&hcnt[pe[i].x >> 17], 1);
    } else {
        for (int e = lo + tid; e < hi; e += 512)
            atomicAdd(&hcnt[stg8[e].x >> 17], 1);
    }
    __syncthreads();
    int deg = (tid < nloc) ? hcnt[tid] : -1;   // capture before cursor reuse
    if (tid < NB_NODES) hinc[tid] = hcnt[tid];
    __syncthreads();
    for (int off = 1; off < NB_NODES; off <<= 1) {
        int v = (tid < NB_NODES && tid >= off) ? hinc[tid - off] : 0;
        __syncthreads();
        if (tid < NB_NODES) hinc[tid] += v;
        __syncthreads();
    }
    if (tid < nloc) {
        int excl = hinc[tid] - hcnt[tid];
        rowptr[n0 + tid] = lo + excl;
        hcnt[tid] = excl;               // reuse as cursor
    }
    if (b == K - 1 && tid == 0) rowptr[N] = hi;
    __syncthreads();
    if (fit) {
        for (int i = tid; i < sz; i += 512) {
            int2 p = pe[i];
            int pos = lo + atomicAdd(&hcnt[p.x >> 17], 1);
            perm[pos] = make_int2(p.x & 0x1FFFF, p.y);
        }
    } else {
        for (int e = lo + tid; e < hi; e += 512) {
            int2 p = stg8[e];
            int pos = lo + atomicAdd(&hcnt[p.x >> 17], 1);
            perm[pos] = make_int2(p.x & 0x1FFFF, p.y);
        }
    }
    // ---- degree-sort the bucket's nodes (counting sort over 64 bins) ----
    int dbin = (deg > 63) ? 63 : deg;
    if (tid < nloc) atomicAdd(&dh[dbin], 1);
    __syncthreads();
    if (tid == 0) {
        int run = 0;
        #pragma unroll
        for (int i = 0; i < 64; ++i) { dof[i] = run; run += dh[i]; dh[i] = 0; }
    }
    __syncthreads();
    if (tid < nloc) {
        int r = dof[dbin] + atomicAdd(&dh[dbin], 1);
        norder[n0 + r] = n0 + tid;
    }
}

// ---------- gather-side aggregation: 8 lanes per node via degree-sorted order --
// lane q owns feature pair-columns [4q,4q+4); 8 nodes/wave with ~equal degree.
__global__ __launch_bounds__(256) void csr_agg(
    const int* __restrict__ rowptr, const int* __restrict__ norder,
    const int2* __restrict__ perm, const __half* __restrict__ A,
    float* __restrict__ out, int N)
{
    int gid = blockIdx.x * 256 + threadIdx.x;
    int idx = gid >> 3;          // 8 threads per node
    if (idx >= N) return;
    int n = norder[idx];
    int q = threadIdx.x & 7;     // uint2 column within 32-half row
    int e0 = rowptr[n], e1 = rowptr[n + 1];
    const uint2* A2 = (const uint2*)A;   // row stride = 8 uint2
    float4 a0 = make_float4(0.f, 0.f, 0.f, 0.f);
    float4 a1 = a0, a2 = a0, a3 = a0;
    int e = e0;
    for (; e + 3 < e1; e += 4) {
        int2 p0 = perm[e];
        int2 p1 = perm[e + 1];
        int2 p2 = perm[e + 2];
        int2 p3 = perm[e + 3];
        uint2 r0 = A2[(size_t)p0.x * 8 + q];
        uint2 r1 = A2[(size_t)p1.x * 8 + q];
        uint2 r2 = A2[(size_t)p2.x * 8 + q];
        uint2 r3 = A2[(size_t)p3.x * 8 + q];
        float w0 = __int_as_float(p0.y), w1 = __int_as_float(p1.y);
        float w2 = __int_as_float(p2.y), w3 = __int_as_float(p3.y);
        float2 f01 = __half22float2(*(__half2*)&r0.x);
        float2 f23 = __half22float2(*(__half2*)&r0.y);
        a0.x = fmaf(f01.x, w0, a0.x); a0.y = fmaf(f01.y, w0, a0.y);
        a0.z = fmaf(f23.x, w0, a0.z); a0.w = fmaf(f23.y, w0, a0.w);
        float2 g01 = __half22float2(*(__half2*)&r1.x);
        float2 g23 = __half22float2(*(__half2*)&r1.y);
        a1.x = fmaf(g01.x, w1, a1.x); a1.y = fmaf(g01.y, w1, a1.y);
        a1.z = fmaf(g23.x, w1, a1.z); a1.w = fmaf(g23.y, w1, a1.w);
        float2 h01 = __half22float2(*(__half2*)&r2.x);
        float2 h23 = __half22float2(*(__half2*)&r2.y);
        a2.x = fmaf(h01.x, w2, a2.x); a2.y = fmaf(h01.y, w2, a2.y);
        a2.z = fmaf(h23.x, w2, a2.z); a2.w = fmaf(h23.y, w2, a2.w);
        float2 k01 = __half22float2(*(__half2*)&r3.x);
        float2 k23 = __half22float2(*(__half2*)&r3.y);
        a3.x = fmaf(k01.x, w3, a3.x); a3.y = fmaf(k01.y, w3, a3.y);
        a3.z = fmaf(k23.x, w3, a3.z); a3.w = fmaf(k23.y, w3, a3.w);
    }
    for (; e < e1; ++e) {
        int2 p = perm[e];
        uint2 r = A2[(size_t)p.x * 8 + q];
        float w = __int_as_float(p.y);
        float2 f01 = __half22float2(*(__half2*)&r.x);
        float2 f23 = __half22float2(*(__half2*)&r.y);
        a0.x = fmaf(f01.x, w, a0.x); a0.y = fmaf(f01.y, w, a0.y);
        a0.z = fmaf(f23.x, w, a0.z); a0.w = fmaf(f23.y, w, a0.w);
    }
    a0.x += a1.x + a2.x + a3.x;
    a0.y += a1.y + a2.y + a3.y;
    a0.z += a1.z + a2.z + a3.z;
    a0.w += a1.w + a2.w + a3.w;
    float4* O4 = (float4*)out;
    size_t oi = (size_t)n * 8 + q;
    float4 o = O4[oi];
    o.x += a0.x; o.y += a0.y; o.z += a0.z; o.w += a0.w;
    O4[oi] = o;
}

// ---------- fused pool + MLP: one block per graph, batch sorted ----------
__global__ __launch_bounds__(256) void pool_mlp(
    const float* __restrict__ C, const int* __restrict__ batch, int N,
    const float* __restrict__ W1, const float* __restrict__ b1,
    const float* __restrict__ W2, const float* __restrict__ b2,
    const float* __restrict__ W3, const float* __restrict__ b3,
    float* __restrict__ out)
{
    int g = blockIdx.x;
    int tid = threadIdx.x;
    int lo, hi;
    {
        int l = 0, r = N;
        while (l < r) { int m = (l + r) >> 1; if (batch[m] < g) l = m + 1; else r = m; }
        lo = l;
        r = N;
        while (l < r) { int m = (l + r) >> 1; if (batch[m] < g + 1) l = m + 1; else r = m; }
        hi = l;
    }
    __shared__ float ssum[8][32];
    __shared__ float gvec[32];
    __shared__ float h1v[32];
    __shared__ float h2v[16];
    int f = tid & 31, seg = tid >> 5;
    float acc = 0.f;
    for (int n = lo + seg; n < hi; n += 8) {
        float v = C[(size_t)n * HID + f];
        acc += v > 0.f ? v : 0.f;
    }
    ssum[seg][f] = acc;
    __syncthreads();
    if (tid < 32) {
        float s = 0.f;
        #pragma unroll
        for (int k = 0; k < 8; ++k) s += ssum[k][tid];
        float c = (float)(hi - lo); c = c > 1.f ? c : 1.f;
        gvec[tid] = s / c;
    }
    __syncthreads();
    if (tid < 32) {
        float a = b1[tid];
        #pragma unroll
        for (int k = 0; k < 32; ++k) a = fmaf(gvec[k], W1[k * 32 + tid], a);
        h1v[tid] = a > 0.f ? a : 0.f;
    }
    __syncthreads();
    if (tid < 16) {
        float a = b2[tid];
        #pragma unroll
        for (int k = 0; k < 32; ++k) a = fmaf(h1v[k], W2[k * 16 + tid], a);
        h2v[tid] = a > 0.f ? a : 0.f;
    }
    __syncthreads();
    if (tid == 0) {
        float o = b3[0];
        #pragma unroll
        for (int k = 0; k < 16; ++k) o = fmaf(h2v[k], W3[k], o);
        out[g] = o;
    }
}

extern "C" void kernel_launch(void* const* d_in, const int* in_sizes, int n_in,
                              void* d_out, int out_size, void* d_ws, size_t ws_size,
                              hipStream_t stream) {
    const float* x     = (const float*)d_in[0];
    const int*   ei    = (const int*)d_in[1];
    const float* ew    = (const float*)d_in[2];
    const int*   batch = (const int*)d_in[3];
    const float* c1rw  = (const float*)d_in[4];
    const float* c1rb  = (const float*)d_in[5];
    const float* c1ow  = (const float*)d_in[6];
    const float* c2rw  = (const float*)d_in[7];
    const float* c2rb  = (const float*)d_in[8];
    const float* c2ow  = (const float*)d_in[9];
    const float* l1w   = (const float*)d_in[10];
    const float* l1b   = (const float*)d_in[11];
    const float* l2w   = (const float*)d_in[12];
    const float* l2b   = (const float*)d_in[13];
    const float* lw    = (const float*)d_in[14];
    const float* lb    = (const float*)d_in[15];

    int N = in_sizes[0] / FIN;      // 100000
    int E = in_sizes[2];            // 1600000
    const int* src = ei;
    const int* dst = ei + E;
    int K    = (N + NB_NODES - 1) >> NB_SHIFT;   // 391 buckets (256 nodes)
    int NBLK = (E + EPB - 1) / EPB;              // 782 edge blocks

    // ---- workspace layout (no aliasing: lin64 runs concurrently with build) ----
    char* ws = (char*)d_ws;
    size_t off = 0;
    auto alloc = [&](size_t nbytes) { void* p = ws + off; off += (nbytes + 255) & ~size_t(255); return p; };
    __half* A      = (__half*)alloc((size_t)N * HID * 2);        // 6.4 MB (fp16)
    float*  BC     = (float*) alloc((size_t)N * HID * 4);        // 12.8 MB
    int2*   perm   = (int2*)  alloc((size_t)E * 8);              // 12.8 MB
    int2*   stg8   = (int2*)  alloc((size_t)E * 8);              // 12.8 MB
    int*    cbb    = (int*)   alloc((size_t)K * NBLK * 4);       // 1.22 MB
    int*    rowptr = (int*)   alloc((size_t)(N + 1) * 4);
    int*    norder = (int*)   alloc((size_t)N * 4);
    int*    btot   = (int*)   alloc((size_t)KMAX2 * 4);
    int*    bbase  = (int*)   alloc((size_t)(KMAX2 + 1) * 4);

    int nb_node = (N + NT - 1) / NT;
    int nb_agg  = (int)(((long long)N * 8 + 255) / 256);   // 8 threads per node

    // fused: histogram (NBLK blocks) || conv1 linear (nb_node blocks)
    hist_lin64<<<NBLK + nb_node, 256, 0, stream>>>(
        dst, cbb, E, K, NBLK, x, c1rw, c1ow, c1rb, A, BC, N);
    // rest of partition build
    bucket_scan<<<K, 256, 0, stream>>>(cbb, btot, NBLK);
    btot_scan<<<1, 256, 0, stream>>>(btot, bbase, K);
    partB<<<NBLK, 256, 0, stream>>>(src, dst, ew, cbb, bbase, stg8, E, K, NBLK);
    partC2<<<K, 512, 0, stream>>>(stg8, bbase, rowptr, perm, norder, N, K);

    // conv1 aggregation (degree-sorted node order)
    csr_agg<<<nb_agg, 256, 0, stream>>>(rowptr, norder, perm, A, BC, N);
    // conv2 (relu fused into node_lin32 load; A overwritten with layer-2 rel-proj)
    node_lin32<<<nb_node, 256, 0, stream>>>(BC, c2rw, c2ow, c2rb, A, BC, N);
    csr_agg<<<nb_agg, 256, 0, stream>>>(rowptr, norder, perm, A, BC, N);
    // fused pool + MLP
    pool_mlp<<<NGRAPH, 256, 0, stream>>>(BC, batch, N, l1w, l1b, l2w, l2b, lw, lb,
                                         (float*)d_out);
}

// Round 19
// 159.121 us; speedup vs baseline: 1.0591x; 1.0591x over previous
//
#include <hip/hip_runtime.h>
#include <hip/hip_fp16.h>

#define NGRAPH 256
#define FIN 64
#define HID 32
#define NB_SHIFT 8            // 256 nodes per bucket
#define NB_NODES 256
#define KMAX2 512
#define EPB 2048              // edges per partition block
#define EPT 8                 // edges per thread (256 threads)
#define NT 64                 // nodes per GEMM block
#define XPAD 65               // 64 + 1 pad (floats) per staged x row
#define HPAD 33               // 32 + 1 pad
#define PCAP 6016             // partC2 LDS edge-staging capacity

// ---------- fused: bucket_hist (blocks [0,NBLK)) + node_lin64 (rest) ----------
union SU {
    int h[KMAX2];
    struct { float Wr[FIN * HID]; float Wo[FIN * HID]; float b[HID];
             float x[NT * XPAD]; } g;
};

__global__ __launch_bounds__(256, 4) void hist_lin64(
    const int* __restrict__ dst, int* __restrict__ cbb, int E, int K, int NBLK,
    const float* __restrict__ x, const float* __restrict__ Wrel,
    const float* __restrict__ Wroot, const float* __restrict__ bias,
    __half* __restrict__ A, float* __restrict__ B, int N)
{
    __shared__ SU u;
    int tid = threadIdx.x;
    if (blockIdx.x < (unsigned)NBLK) {
        // ---- histogram role ----
        for (int i = tid; i < K; i += 256) u.h[i] = 0;
        __syncthreads();
        int e0 = blockIdx.x * EPB + tid * 8;
        if (e0 + 7 < E) {
            int4 d0 = *reinterpret_cast<const int4*>(dst + e0);
            int4 d1 = *reinterpret_cast<const int4*>(dst + e0 + 4);
            atomicAdd(&u.h[d0.x >> NB_SHIFT], 1); atomicAdd(&u.h[d0.y >> NB_SHIFT], 1);
            atomicAdd(&u.h[d0.z >> NB_SHIFT], 1); atomicAdd(&u.h[d0.w >> NB_SHIFT], 1);
            atomicAdd(&u.h[d1.x >> NB_SHIFT], 1); atomicAdd(&u.h[d1.y >> NB_SHIFT], 1);
            atomicAdd(&u.h[d1.z >> NB_SHIFT], 1); atomicAdd(&u.h[d1.w >> NB_SHIFT], 1);
        } else {
            for (int e = e0; e < E && e < e0 + 8; ++e)
                atomicAdd(&u.h[dst[e] >> NB_SHIFT], 1);
        }
        __syncthreads();
        for (int i = tid; i < K; i += 256)
            cbb[(size_t)i * NBLK + blockIdx.x] = u.h[i];
        return;
    }
    // ---- conv1 linear role ----
    {
        const float4* Wr4 = (const float4*)Wrel;
        const float4* Wo4 = (const float4*)Wroot;
        for (int i = tid; i < FIN * HID / 4; i += 256) {
            ((float4*)u.g.Wr)[i] = Wr4[i];
            ((float4*)u.g.Wo)[i] = Wo4[i];
        }
        if (tid < HID) u.g.b[tid] = bias[tid];
    }
    int base = (blockIdx.x - NBLK) * NT;
    {
        const float4* x4 = (const float4*)x;
        for (int i = tid; i < NT * 16; i += 256) {
            int row = i >> 4, c4 = i & 15;
            int n = base + row;
            float4 v = (n < N) ? x4[(size_t)n * 16 + c4]
                               : make_float4(0.f, 0.f, 0.f, 0.f);
            *(float4*)&u.g.x[row * XPAD + c4 * 4] = v;
        }
    }
    __syncthreads();

    int nl = tid >> 3;          // 0..31
    int fq = (tid & 7) * 4;     // feature quad base
    const float* xa = &u.g.x[nl * XPAD];
    const float* xb = &u.g.x[(nl + 32) * XPAD];
    float4 ar0 = make_float4(0.f,0.f,0.f,0.f), ao0 = ar0;
    float4 ar1 = ar0, ao1 = ar0;
    #pragma unroll 4
    for (int k = 0; k < FIN; ++k) {
        float4 w4 = *(const float4*)&u.g.Wr[k * HID + fq];
        float4 o4 = *(const float4*)&u.g.Wo[k * HID + fq];
        float va = xa[k], vb = xb[k];
        ar0.x = fmaf(va, w4.x, ar0.x); ar0.y = fmaf(va, w4.y, ar0.y);
        ar0.z = fmaf(va, w4.z, ar0.z); ar0.w = fmaf(va, w4.w, ar0.w);
        ao0.x = fmaf(va, o4.x, ao0.x); ao0.y = fmaf(va, o4.y, ao0.y);
        ao0.z = fmaf(va, o4.z, ao0.z); ao0.w = fmaf(va, o4.w, ao0.w);
        ar1.x = fmaf(vb, w4.x, ar1.x); ar1.y = fmaf(vb, w4.y, ar1.y);
        ar1.z = fmaf(vb, w4.z, ar1.z); ar1.w = fmaf(vb, w4.w, ar1.w);
        ao1.x = fmaf(vb, o4.x, ao1.x); ao1.y = fmaf(vb, o4.y, ao1.y);
        ao1.z = fmaf(vb, o4.z, ao1.z); ao1.w = fmaf(vb, o4.w, ao1.w);
    }
    float4 bb = *(const float4*)&u.g.b[fq];
    int n0 = base + nl, n1 = base + nl + 32;
    if (n0 < N) {
        __half2 pa = __floats2half2_rn(ar0.x, ar0.y);
        __half2 pb = __floats2half2_rn(ar0.z, ar0.w);
        uint2 pk; pk.x = *(unsigned*)&pa; pk.y = *(unsigned*)&pb;
        *(uint2*)&A[(size_t)n0 * HID + fq] = pk;
        ao0.x += bb.x; ao0.y += bb.y; ao0.z += bb.z; ao0.w += bb.w;
        *(float4*)&B[(size_t)n0 * HID + fq] = ao0;
    }
    if (n1 < N) {
        __half2 pa = __floats2half2_rn(ar1.x, ar1.y);
        __half2 pb = __floats2half2_rn(ar1.z, ar1.w);
        uint2 pk; pk.x = *(unsigned*)&pa; pk.y = *(unsigned*)&pb;
        *(uint2*)&A[(size_t)n1 * HID + fq] = pk;
        ao1.x += bb.x; ao1.y += bb.y; ao1.z += bb.z; ao1.w += bb.w;
        *(float4*)&B[(size_t)n1 * HID + fq] = ao1;
    }
}

// ---------- node GEMM 2: relu fused on load, FIN=32 ----------
__global__ __launch_bounds__(256, 4) void node_lin32(
    const float* __restrict__ Hpre, const float* __restrict__ Wrel,
    const float* __restrict__ Wroot, const float* __restrict__ bias,
    __half* __restrict__ A, float* __restrict__ C, int N)
{
    __shared__ float sWr[HID * HID];      // 4 KB
    __shared__ float sWo[HID * HID];
    __shared__ float sb[HID];
    __shared__ float sh[NT * HPAD];       // 8.4 KB
    int tid = threadIdx.x;
    {
        const float4* Wr4 = (const float4*)Wrel;
        const float4* Wo4 = (const float4*)Wroot;
        for (int i = tid; i < HID * HID / 4; i += 256) {
            ((float4*)sWr)[i] = Wr4[i];
            ((float4*)sWo)[i] = Wo4[i];
        }
        if (tid < HID) sb[tid] = bias[tid];
    }
    int base = blockIdx.x * NT;
    {
        const float4* H4 = (const float4*)Hpre;
        for (int i = tid; i < NT * 8; i += 256) {
            int row = i >> 3, c4 = i & 7;
            int n = base + row;
            float4 v = make_float4(0.f, 0.f, 0.f, 0.f);
            if (n < N) {
                v = H4[(size_t)n * 8 + c4];
                v.x = v.x > 0.f ? v.x : 0.f; v.y = v.y > 0.f ? v.y : 0.f;
                v.z = v.z > 0.f ? v.z : 0.f; v.w = v.w > 0.f ? v.w : 0.f;
            }
            *(float4*)&sh[row * HPAD + c4 * 4] = v;
        }
    }
    __syncthreads();

    int nl = tid >> 3;
    int fq = (tid & 7) * 4;
    const float* xa = &sh[nl * HPAD];
    const float* xb = &sh[(nl + 32) * HPAD];
    float4 ar0 = make_float4(0.f,0.f,0.f,0.f), ao0 = ar0;
    float4 ar1 = ar0, ao1 = ar0;
    #pragma unroll 4
    for (int k = 0; k < HID; ++k) {
        float4 w4 = *(const float4*)&sWr[k * HID + fq];
        float4 o4 = *(const float4*)&sWo[k * HID + fq];
        float va = xa[k], vb = xb[k];
        ar0.x = fmaf(va, w4.x, ar0.x); ar0.y = fmaf(va, w4.y, ar0.y);
        ar0.z = fmaf(va, w4.z, ar0.z); ar0.w = fmaf(va, w4.w, ar0.w);
        ao0.x = fmaf(va, o4.x, ao0.x); ao0.y = fmaf(va, o4.y, ao0.y);
        ao0.z = fmaf(va, o4.z, ao0.z); ao0.w = fmaf(va, o4.w, ao0.w);
        ar1.x = fmaf(vb, w4.x, ar1.x); ar1.y = fmaf(vb, w4.y, ar1.y);
        ar1.z = fmaf(vb, w4.z, ar1.z); ar1.w = fmaf(vb, w4.w, ar1.w);
        ao1.x = fmaf(vb, o4.x, ao1.x); ao1.y = fmaf(vb, o4.y, ao1.y);
        ao1.z = fmaf(vb, o4.z, ao1.z); ao1.w = fmaf(vb, o4.w, ao1.w);
    }
    float4 bb = *(const float4*)&sb[fq];
    int n0 = base + nl, n1 = base + nl + 32;
    if (n0 < N) {
        __half2 pa = __floats2half2_rn(ar0.x, ar0.y);
        __half2 pb = __floats2half2_rn(ar0.z, ar0.w);
        uint2 pk; pk.x = *(unsigned*)&pa; pk.y = *(unsigned*)&pb;
        *(uint2*)&A[(size_t)n0 * HID + fq] = pk;
        ao0.x += bb.x; ao0.y += bb.y; ao0.z += bb.z; ao0.w += bb.w;
        *(float4*)&C[(size_t)n0 * HID + fq] = ao0;
    }
    if (n1 < N) {
        __half2 pa = __floats2half2_rn(ar1.x, ar1.y);
        __half2 pb = __floats2half2_rn(ar1.z, ar1.w);
        uint2 pk; pk.x = *(unsigned*)&pa; pk.y = *(unsigned*)&pb;
        *(uint2*)&A[(size_t)n1 * HID + fq] = pk;
        ao1.x += bb.x; ao1.y += bb.y; ao1.z += bb.z; ao1.w += bb.w;
        *(float4*)&C[(size_t)n1 * HID + fq] = ao1;
    }
}

// ---------- rest of the deterministic partition build ----------

__global__ __launch_bounds__(256) void bucket_scan(
    int* __restrict__ cbb, int* __restrict__ btot, int NBLK)
{
    __shared__ int sc[256];
    size_t row = (size_t)blockIdx.x * NBLK;
    int t = threadIdx.x;
    int base = t * 4;
    int v[4]; int s = 0;
    #pragma unroll
    for (int j = 0; j < 4; ++j) { v[j] = (base + j < NBLK) ? cbb[row + base + j] : 0; s += v[j]; }
    sc[t] = s;
    __syncthreads();
    int acc = s;
    for (int off = 1; off < 256; off <<= 1) {
        int add = (t >= off) ? sc[t - off] : 0;
        __syncthreads();
        acc += add;
        sc[t] = acc;
        __syncthreads();
    }
    int run = acc - s;
    #pragma unroll
    for (int j = 0; j < 4; ++j) {
        if (base + j < NBLK) cbb[row + base + j] = run;
        run += v[j];
    }
    if (t == 255) btot[blockIdx.x] = acc;
}

__global__ __launch_bounds__(256) void btot_scan(
    const int* __restrict__ btot, int* __restrict__ bbase, int K)
{
    __shared__ int sc[256];
    int t = threadIdx.x;
    int base = t * 4;
    int v[4]; int s = 0;
    #pragma unroll
    for (int j = 0; j < 4; ++j) { v[j] = (base + j < K) ? btot[base + j] : 0; s += v[j]; }
    sc[t] = s;
    __syncthreads();
    int acc = s;
    for (int off = 1; off < 256; off <<= 1) {
        int add = (t >= off) ? sc[t - off] : 0;
        __syncthreads();
        acc += add;
        sc[t] = acc;
        __syncthreads();
    }
    int run = acc - s;
    #pragma unroll
    for (int j = 0; j < 4; ++j) {
        if (base + j < K) bbase[base + j] = run;
        run += v[j];
    }
    if (t == 255) bbase[K] = acc;
}

// partition: edges -> bucket-grouped staging; payload = {src | dloc<<17, ew}
__global__ __launch_bounds__(256) void partB(
    const int* __restrict__ src, const int* __restrict__ dst,
    const float* __restrict__ ew, const int* __restrict__ cbb,
    const int* __restrict__ bbase, int2* __restrict__ stg8,
    int E, int K, int NBLK)
{
    __shared__ int4 pay[EPB];       // 32 KB: {meta, ew, tgt, pad}
    __shared__ int h[KMAX2];
    __shared__ int lofs[KMAX2];
    __shared__ int gb[KMAX2];
    __shared__ int sc[256];
    int tid = threadIdx.x;
    for (int i = tid; i < K; i += 256) h[i] = 0;
    __syncthreads();

    int base = blockIdx.x * EPB;
    int es[EPT], ds[EPT]; float wsr[EPT];
    #pragma unroll
    for (int k = 0; k < EPT; ++k) {
        int e = base + k * 256 + tid;
        if (e < E) {
            es[k] = src[e]; ds[k] = dst[e]; wsr[k] = ew[e];
            atomicAdd(&h[ds[k] >> NB_SHIFT], 1);
        } else ds[k] = -1;
    }
    __syncthreads();

    int b0 = tid * 2;
    int v0 = (b0 < K) ? h[b0] : 0;
    int v1 = (b0 + 1 < K) ? h[b0 + 1] : 0;
    int s = v0 + v1;
    sc[tid] = s;
    __syncthreads();
    int acc = s;
    for (int off = 1; off < 256; off <<= 1) {
        int add = (tid >= off) ? sc[tid - off] : 0;
        __syncthreads();
        acc += add;
        sc[tid] = acc;
        __syncthreads();
    }
    int run = acc - s;
    if (b0 < K) lofs[b0] = run;
    if (b0 + 1 < K) lofs[b0 + 1] = run + v0;
    __syncthreads();

    for (int b = tid; b < K; b += 256) {
        gb[b] = bbase[b] + cbb[(size_t)b * NBLK + blockIdx.x];
        h[b] = lofs[b];
    }
    __syncthreads();

    #pragma unroll
    for (int k = 0; k < EPT; ++k) {
        if (ds[k] >= 0) {
            int b = ds[k] >> NB_SHIFT;
            int dloc = ds[k] & (NB_NODES - 1);
            int slot = atomicAdd(&h[b], 1);
            pay[slot] = make_int4(es[k] | (dloc << 17), __float_as_int(wsr[k]),
                                  gb[b] + slot - lofs[b], 0);
        }
    }
    __syncthreads();

    int tot = E - base; if (tot > EPB) tot = EPB;
    for (int i = tid; i < tot; i += 256) {
        int4 p = pay[i];
        stg8[p.z] = make_int2(p.x, p.y);
    }
}

// per bucket: counting-sort edges by dst node, LDS-staged single-pass
__global__ __launch_bounds__(512) void partC2(
    const int2* __restrict__ stg8, const int* __restrict__ bbase,
    int* __restrict__ rowptr, int2* __restrict__ perm, int N, int K)
{
    __shared__ int2 pe[PCAP];          // 47 KB edge staging
    __shared__ int hcnt[NB_NODES];
    __shared__ int hinc[NB_NODES];
    int b = blockIdx.x;
    int n0 = b << NB_SHIFT;
    int nTop = n0 + NB_NODES; if (nTop > N) nTop = N;
    int nloc = nTop - n0;
    int tid = threadIdx.x;
    if (tid < NB_NODES) hcnt[tid] = 0;
    int lo = bbase[b], hi = bbase[b + 1];
    int sz = hi - lo;
    bool fit = (sz <= PCAP);
    if (fit) {
        for (int i = tid; i < sz; i += 512) pe[i] = stg8[lo + i];
    }
    __syncthreads();
    if (fit) {
        for (int i = tid; i < sz; i += 512)
            atomicAdd(&hcnt[pe[i].x >> 17], 1);
    } else {
        for (int e = lo + tid; e < hi; e += 512)
            atomicAdd(&hcnt[stg8[e].x >> 17], 1);
    }
    __syncthreads();
    if (tid < NB_NODES) hinc[tid] = hcnt[tid];
    __syncthreads();
    for (int off = 1; off < NB_NODES; off <<= 1) {
        int v = (tid < NB_NODES && tid >= off) ? hinc[tid - off] : 0;
        __syncthreads();
        if (tid < NB_NODES) hinc[tid] += v;
        __syncthreads();
    }
    if (tid < nloc) {
        int excl = hinc[tid] - hcnt[tid];
        rowptr[n0 + tid] = lo + excl;
        hcnt[tid] = excl;               // reuse as cursor
    }
    if (b == K - 1 && tid == 0) rowptr[N] = hi;
    __syncthreads();
    if (fit) {
        for (int i = tid; i < sz; i += 512) {
            int2 p = pe[i];
            int pos = lo + atomicAdd(&hcnt[p.x >> 17], 1);
            perm[pos] = make_int2(p.x & 0x1FFFF, p.y);
        }
    } else {
        for (int e = lo + tid; e < hi; e += 512) {
            int2 p = stg8[e];
            int pos = lo + atomicAdd(&hcnt[p.x >> 17], 1);
            perm[pos] = make_int2(p.x & 0x1FFFF, p.y);
        }
    }
}

// ---------- gather-side aggregation: 4 lanes per node, no cross-lane reduce ----
// lane q of a node owns features [8q, 8q+8) via one uint4 (16 B) load per edge;
// 16 nodes per wave -> 16 independent chains; perm loads amortized over 4 lanes.
__global__ __launch_bounds__(256) void csr_agg(
    const int* __restrict__ rowptr, const int2* __restrict__ perm,
    const __half* __restrict__ A, float* __restrict__ out, int N)
{
    int gid = blockIdx.x * 256 + threadIdx.x;
    int n = gid >> 2;            // 4 threads per node
    if (n >= N) return;
    int q = threadIdx.x & 3;     // uint4 column within 32-half row
    int e0 = rowptr[n], e1 = rowptr[n + 1];
    const uint4* A4 = (const uint4*)A;   // row stride = 4 uint4
    float a0[8] = {0.f,0.f,0.f,0.f,0.f,0.f,0.f,0.f};
    float a1[8] = {0.f,0.f,0.f,0.f,0.f,0.f,0.f,0.f};
    int e = e0;
    for (; e + 1 < e1; e += 2) {
        int2 p0 = perm[e];
        int2 p1 = perm[e + 1];
        uint4 r0 = A4[(size_t)p0.x * 4 + q];
        uint4 r1 = A4[(size_t)p1.x * 4 + q];
        float w0 = __int_as_float(p0.y), w1 = __int_as_float(p1.y);
        float2 c0 = __half22float2(*(__half2*)&r0.x);
        float2 c1 = __half22float2(*(__half2*)&r0.y);
        float2 c2 = __half22float2(*(__half2*)&r0.z);
        float2 c3 = __half22float2(*(__half2*)&r0.w);
        a0[0] = fmaf(c0.x, w0, a0[0]); a0[1] = fmaf(c0.y, w0, a0[1]);
        a0[2] = fmaf(c1.x, w0, a0[2]); a0[3] = fmaf(c1.y, w0, a0[3]);
        a0[4] = fmaf(c2.x, w0, a0[4]); a0[5] = fmaf(c2.y, w0, a0[5]);
        a0[6] = fmaf(c3.x, w0, a0[6]); a0[7] = fmaf(c3.y, w0, a0[7]);
        float2 d0 = __half22float2(*(__half2*)&r1.x);
        float2 d1 = __half22float2(*(__half2*)&r1.y);
        float2 d2 = __half22float2(*(__half2*)&r1.z);
        float2 d3 = __half22float2(*(__half2*)&r1.w);
        a1[0] = fmaf(d0.x, w1, a1[0]); a1[1] = fmaf(d0.y, w1, a1[1]);
        a1[2] = fmaf(d1.x, w1, a1[2]); a1[3] = fmaf(d1.y, w1, a1[3]);
        a1[4] = fmaf(d2.x, w1, a1[4]); a1[5] = fmaf(d2.y, w1, a1[5]);
        a1[6] = fmaf(d3.x, w1, a1[6]); a1[7] = fmaf(d3.y, w1, a1[7]);
    }
    if (e < e1) {
        int2 p = perm[e];
        uint4 r = A4[(size_t)p.x * 4 + q];
        float w = __int_as_float(p.y);
        float2 c0 = __half22float2(*(__half2*)&r.x);
        float2 c1 = __half22float2(*(__half2*)&r.y);
        float2 c2 = __half22float2(*(__half2*)&r.z);
        float2 c3 = __half22float2(*(__half2*)&r.w);
        a0[0] = fmaf(c0.x, w, a0[0]); a0[1] = fmaf(c0.y, w, a0[1]);
        a0[2] = fmaf(c1.x, w, a0[2]); a0[3] = fmaf(c1.y, w, a0[3]);
        a0[4] = fmaf(c2.x, w, a0[4]); a0[5] = fmaf(c2.y, w, a0[5]);
        a0[6] = fmaf(c3.x, w, a0[6]); a0[7] = fmaf(c3.y, w, a0[7]);
    }
    #pragma unroll
    for (int i = 0; i < 8; ++i) a0[i] += a1[i];
    float4* O4 = (float4*)out;
    size_t oi = (size_t)n * 8 + q * 2;
    float4 o = O4[oi];
    o.x += a0[0]; o.y += a0[1]; o.z += a0[2]; o.w += a0[3];
    O4[oi] = o;
    float4 p = O4[oi + 1];
    p.x += a0[4]; p.y += a0[5]; p.z += a0[6]; p.w += a0[7];
    O4[oi + 1] = p;
}

// ---------- fused pool + MLP: one block per graph, batch sorted ----------
__global__ __launch_bounds__(256) void pool_mlp(
    const float* __restrict__ C, const int* __restrict__ batch, int N,
    const float* __restrict__ W1, const float* __restrict__ b1,
    const float* __restrict__ W2, const float* __restrict__ b2,
    const float* __restrict__ W3, const float* __restrict__ b3,
    float* __restrict__ out)
{
    int g = blockIdx.x;
    int tid = threadIdx.x;
    int lo, hi;
    {
        int l = 0, r = N;
        while (l < r) { int m = (l + r) >> 1; if (batch[m] < g) l = m + 1; else r = m; }
        lo = l;
        r = N;
        while (l < r) { int m = (l + r) >> 1; if (batch[m] < g + 1) l = m + 1; else r = m; }
        hi = l;
    }
    __shared__ float ssum[8][32];
    __shared__ float gvec[32];
    __shared__ float h1v[32];
    __shared__ float h2v[16];
    int f = tid & 31, seg = tid >> 5;
    float acc = 0.f;
    for (int n = lo + seg; n < hi; n += 8) {
        float v = C[(size_t)n * HID + f];
        acc += v > 0.f ? v : 0.f;
    }
    ssum[seg][f] = acc;
    __syncthreads();
    if (tid < 32) {
        float s = 0.f;
        #pragma unroll
        for (int k = 0; k < 8; ++k) s += ssum[k][tid];
        float c = (float)(hi - lo); c = c > 1.f ? c : 1.f;
        gvec[tid] = s / c;
    }
    __syncthreads();
    if (tid < 32) {
        float a = b1[tid];
        #pragma unroll
        for (int k = 0; k < 32; ++k) a = fmaf(gvec[k], W1[k * 32 + tid], a);
        h1v[tid] = a > 0.f ? a : 0.f;
    }
    __syncthreads();
    if (tid < 16) {
        float a = b2[tid];
        #pragma unroll
        for (int k = 0; k < 32; ++k) a = fmaf(h1v[k], W2[k * 16 + tid], a);
        h2v[tid] = a > 0.f ? a : 0.f;
    }
    __syncthreads();
    if (tid == 0) {
        float o = b3[0];
        #pragma unroll
        for (int k = 0; k < 16; ++k) o = fmaf(h2v[k], W3[k], o);
        out[g] = o;
    }
}

extern "C" void kernel_launch(void* const* d_in, const int* in_sizes, int n_in,
                              void* d_out, int out_size, void* d_ws, size_t ws_size,
                              hipStream_t stream) {
    const float* x     = (const float*)d_in[0];
    const int*   ei    = (const int*)d_in[1];
    const float* ew    = (const float*)d_in[2];
    const int*   batch = (const int*)d_in[3];
    const float* c1rw  = (const float*)d_in[4];
    const float* c1rb  = (const float*)d_in[5];
    const float* c1ow  = (const float*)d_in[6];
    const float* c2rw  = (const float*)d_in[7];
    const float* c2rb  = (const float*)d_in[8];
    const float* c2ow  = (const float*)d_in[9];
    const float* l1w   = (const float*)d_in[10];
    const float* l1b   = (const float*)d_in[11];
    const float* l2w   = (const float*)d_in[12];
    const float* l2b   = (const float*)d_in[13];
    const float* lw    = (const float*)d_in[14];
    const float* lb    = (const float*)d_in[15];

    int N = in_sizes[0] / FIN;      // 100000
    int E = in_sizes[2];            // 1600000
    const int* src = ei;
    const int* dst = ei + E;
    int K    = (N + NB_NODES - 1) >> NB_SHIFT;   // 391 buckets (256 nodes)
    int NBLK = (E + EPB - 1) / EPB;              // 782 edge blocks

    // ---- workspace layout (no aliasing: lin64 runs concurrently with build) ----
    char* ws = (char*)d_ws;
    size_t off = 0;
    auto alloc = [&](size_t nbytes) { void* p = ws + off; off += (nbytes + 255) & ~size_t(255); return p; };
    __half* A      = (__half*)alloc((size_t)N * HID * 2);        // 6.4 MB (fp16)
    float*  BC     = (float*) alloc((size_t)N * HID * 4);        // 12.8 MB
    int2*   perm   = (int2*)  alloc((size_t)E * 8);              // 12.8 MB
    int2*   stg8   = (int2*)  alloc((size_t)E * 8);              // 12.8 MB
    int*    cbb    = (int*)   alloc((size_t)K * NBLK * 4);       // 1.22 MB
    int*    rowptr = (int*)   alloc((size_t)(N + 1) * 4);
    int*    btot   = (int*)   alloc((size_t)KMAX2 * 4);
    int*    bbase  = (int*)   alloc((size_t)(KMAX2 + 1) * 4);

    int nb_node = (N + NT - 1) / NT;
    int nb_agg  = (int)(((long long)N * 4 + 255) / 256);   // 4 threads per node

    // fused: histogram (NBLK blocks) || conv1 linear (nb_node blocks)
    hist_lin64<<<NBLK + nb_node, 256, 0, stream>>>(
        dst, cbb, E, K, NBLK, x, c1rw, c1ow, c1rb, A, BC, N);
    // rest of partition build
    bucket_scan<<<K, 256, 0, stream>>>(cbb, btot, NBLK);
    btot_scan<<<1, 256, 0, stream>>>(btot, bbase, K);
    partB<<<NBLK, 256, 0, stream>>>(src, dst, ew, cbb, bbase, stg8, E, K, NBLK);
    partC2<<<K, 512, 0, stream>>>(stg8, bbase, rowptr, perm, N, K);

    // conv1 aggregation
    csr_agg<<<nb_agg, 256, 0, stream>>>(rowptr, perm, A, BC, N);
    // conv2 (relu fused into node_lin32 load; A overwritten with layer-2 rel-proj)
    node_lin32<<<nb_node, 256, 0, stream>>>(BC, c2rw, c2ow, c2rb, A, BC, N);
    csr_agg<<<nb_agg, 256, 0, stream>>>(rowptr, perm, A, BC, N);
    // fused pool + MLP
    pool_mlp<<<NGRAPH, 256, 0, stream>>>(BC, batch, N, l1w, l1b, l2w, l2b, lw, lb,
                                         (float*)d_out);
}

// Round 20
// 153.745 us; speedup vs baseline: 1.0961x; 1.0350x over previous
//
#include <hip/hip_runtime.h>
#include <hip/hip_fp16.h>

#define NGRAPH 256
#define FIN 64
#define HID 32
#define NB_SHIFT 8            // 256 nodes per bucket
#define NB_NODES 256
#define KMAX2 512
#define EPB 4096              // edges per partition block (hist + partB)
#define NT 64                 // nodes per GEMM block
#define XPAD 65               // 64 + 1 pad (floats) per staged x row
#define HPAD 33               // 32 + 1 pad
#define PCAP 6016             // partC2 LDS edge-staging capacity

// ---------- fused: bucket_hist (blocks [0,NBLK)) + node_lin64 (rest) ----------
union SU {
    int h[KMAX2];
    struct { float Wr[FIN * HID]; float Wo[FIN * HID]; float b[HID];
             float x[NT * XPAD]; } g;
};

__global__ __launch_bounds__(256, 4) void hist_lin64(
    const int* __restrict__ dst, int* __restrict__ cbb, int E, int K, int NBLK,
    const float* __restrict__ x, const float* __restrict__ Wrel,
    const float* __restrict__ Wroot, const float* __restrict__ bias,
    __half* __restrict__ A, float* __restrict__ B, int N)
{
    __shared__ SU u;
    int tid = threadIdx.x;
    if (blockIdx.x < (unsigned)NBLK) {
        // ---- histogram role: 256 threads x 16 edges ----
        for (int i = tid; i < K; i += 256) u.h[i] = 0;
        __syncthreads();
        int e0 = blockIdx.x * EPB + tid * 16;
        if (e0 + 15 < E) {
            #pragma unroll
            for (int c = 0; c < 4; ++c) {
                int4 d = *reinterpret_cast<const int4*>(dst + e0 + c * 4);
                atomicAdd(&u.h[d.x >> NB_SHIFT], 1);
                atomicAdd(&u.h[d.y >> NB_SHIFT], 1);
                atomicAdd(&u.h[d.z >> NB_SHIFT], 1);
                atomicAdd(&u.h[d.w >> NB_SHIFT], 1);
            }
        } else {
            for (int e = e0; e < E && e < e0 + 16; ++e)
                atomicAdd(&u.h[dst[e] >> NB_SHIFT], 1);
        }
        __syncthreads();
        for (int i = tid; i < K; i += 256)
            cbb[(size_t)i * NBLK + blockIdx.x] = u.h[i];
        return;
    }
    // ---- conv1 linear role ----
    {
        const float4* Wr4 = (const float4*)Wrel;
        const float4* Wo4 = (const float4*)Wroot;
        for (int i = tid; i < FIN * HID / 4; i += 256) {
            ((float4*)u.g.Wr)[i] = Wr4[i];
            ((float4*)u.g.Wo)[i] = Wo4[i];
        }
        if (tid < HID) u.g.b[tid] = bias[tid];
    }
    int base = (blockIdx.x - NBLK) * NT;
    {
        const float4* x4 = (const float4*)x;
        for (int i = tid; i < NT * 16; i += 256) {
            int row = i >> 4, c4 = i & 15;
            int n = base + row;
            float4 v = (n < N) ? x4[(size_t)n * 16 + c4]
                               : make_float4(0.f, 0.f, 0.f, 0.f);
            *(float4*)&u.g.x[row * XPAD + c4 * 4] = v;
        }
    }
    __syncthreads();

    int nl = tid >> 3;          // 0..31
    int fq = (tid & 7) * 4;     // feature quad base
    const float* xa = &u.g.x[nl * XPAD];
    const float* xb = &u.g.x[(nl + 32) * XPAD];
    float4 ar0 = make_float4(0.f,0.f,0.f,0.f), ao0 = ar0;
    float4 ar1 = ar0, ao1 = ar0;
    #pragma unroll 4
    for (int k = 0; k < FIN; ++k) {
        float4 w4 = *(const float4*)&u.g.Wr[k * HID + fq];
        float4 o4 = *(const float4*)&u.g.Wo[k * HID + fq];
        float va = xa[k], vb = xb[k];
        ar0.x = fmaf(va, w4.x, ar0.x); ar0.y = fmaf(va, w4.y, ar0.y);
        ar0.z = fmaf(va, w4.z, ar0.z); ar0.w = fmaf(va, w4.w, ar0.w);
        ao0.x = fmaf(va, o4.x, ao0.x); ao0.y = fmaf(va, o4.y, ao0.y);
        ao0.z = fmaf(va, o4.z, ao0.z); ao0.w = fmaf(va, o4.w, ao0.w);
        ar1.x = fmaf(vb, w4.x, ar1.x); ar1.y = fmaf(vb, w4.y, ar1.y);
        ar1.z = fmaf(vb, w4.z, ar1.z); ar1.w = fmaf(vb, w4.w, ar1.w);
        ao1.x = fmaf(vb, o4.x, ao1.x); ao1.y = fmaf(vb, o4.y, ao1.y);
        ao1.z = fmaf(vb, o4.z, ao1.z); ao1.w = fmaf(vb, o4.w, ao1.w);
    }
    float4 bb = *(const float4*)&u.g.b[fq];
    int n0 = base + nl, n1 = base + nl + 32;
    if (n0 < N) {
        __half2 pa = __floats2half2_rn(ar0.x, ar0.y);
        __half2 pb = __floats2half2_rn(ar0.z, ar0.w);
        uint2 pk; pk.x = *(unsigned*)&pa; pk.y = *(unsigned*)&pb;
        *(uint2*)&A[(size_t)n0 * HID + fq] = pk;
        ao0.x += bb.x; ao0.y += bb.y; ao0.z += bb.z; ao0.w += bb.w;
        *(float4*)&B[(size_t)n0 * HID + fq] = ao0;
    }
    if (n1 < N) {
        __half2 pa = __floats2half2_rn(ar1.x, ar1.y);
        __half2 pb = __floats2half2_rn(ar1.z, ar1.w);
        uint2 pk; pk.x = *(unsigned*)&pa; pk.y = *(unsigned*)&pb;
        *(uint2*)&A[(size_t)n1 * HID + fq] = pk;
        ao1.x += bb.x; ao1.y += bb.y; ao1.z += bb.z; ao1.w += bb.w;
        *(float4*)&B[(size_t)n1 * HID + fq] = ao1;
    }
}

// ---------- node GEMM 2: relu fused on load, FIN=32 ----------
__global__ __launch_bounds__(256, 4) void node_lin32(
    const float* __restrict__ Hpre, const float* __restrict__ Wrel,
    const float* __restrict__ Wroot, const float* __restrict__ bias,
    __half* __restrict__ A, float* __restrict__ C, int N)
{
    __shared__ float sWr[HID * HID];      // 4 KB
    __shared__ float sWo[HID * HID];
    __shared__ float sb[HID];
    __shared__ float sh[NT * HPAD];       // 8.4 KB
    int tid = threadIdx.x;
    {
        const float4* Wr4 = (const float4*)Wrel;
        const float4* Wo4 = (const float4*)Wroot;
        for (int i = tid; i < HID * HID / 4; i += 256) {
            ((float4*)sWr)[i] = Wr4[i];
            ((float4*)sWo)[i] = Wo4[i];
        }
        if (tid < HID) sb[tid] = bias[tid];
    }
    int base = blockIdx.x * NT;
    {
        const float4* H4 = (const float4*)Hpre;
        for (int i = tid; i < NT * 8; i += 256) {
            int row = i >> 3, c4 = i & 7;
            int n = base + row;
            float4 v = make_float4(0.f, 0.f, 0.f, 0.f);
            if (n < N) {
                v = H4[(size_t)n * 8 + c4];
                v.x = v.x > 0.f ? v.x : 0.f; v.y = v.y > 0.f ? v.y : 0.f;
                v.z = v.z > 0.f ? v.z : 0.f; v.w = v.w > 0.f ? v.w : 0.f;
            }
            *(float4*)&sh[row * HPAD + c4 * 4] = v;
        }
    }
    __syncthreads();

    int nl = tid >> 3;
    int fq = (tid & 7) * 4;
    const float* xa = &sh[nl * HPAD];
    const float* xb = &sh[(nl + 32) * HPAD];
    float4 ar0 = make_float4(0.f,0.f,0.f,0.f), ao0 = ar0;
    float4 ar1 = ar0, ao1 = ar0;
    #pragma unroll 4
    for (int k = 0; k < HID; ++k) {
        float4 w4 = *(const float4*)&sWr[k * HID + fq];
        float4 o4 = *(const float4*)&sWo[k * HID + fq];
        float va = xa[k], vb = xb[k];
        ar0.x = fmaf(va, w4.x, ar0.x); ar0.y = fmaf(va, w4.y, ar0.y);
        ar0.z = fmaf(va, w4.z, ar0.z); ar0.w = fmaf(va, w4.w, ar0.w);
        ao0.x = fmaf(va, o4.x, ao0.x); ao0.y = fmaf(va, o4.y, ao0.y);
        ao0.z = fmaf(va, o4.z, ao0.z); ao0.w = fmaf(va, o4.w, ao0.w);
        ar1.x = fmaf(vb, w4.x, ar1.x); ar1.y = fmaf(vb, w4.y, ar1.y);
        ar1.z = fmaf(vb, w4.z, ar1.z); ar1.w = fmaf(vb, w4.w, ar1.w);
        ao1.x = fmaf(vb, o4.x, ao1.x); ao1.y = fmaf(vb, o4.y, ao1.y);
        ao1.z = fmaf(vb, o4.z, ao1.z); ao1.w = fmaf(vb, o4.w, ao1.w);
    }
    float4 bb = *(const float4*)&sb[fq];
    int n0 = base + nl, n1 = base + nl + 32;
    if (n0 < N) {
        __half2 pa = __floats2half2_rn(ar0.x, ar0.y);
        __half2 pb = __floats2half2_rn(ar0.z, ar0.w);
        uint2 pk; pk.x = *(unsigned*)&pa; pk.y = *(unsigned*)&pb;
        *(uint2*)&A[(size_t)n0 * HID + fq] = pk;
        ao0.x += bb.x; ao0.y += bb.y; ao0.z += bb.z; ao0.w += bb.w;
        *(float4*)&C[(size_t)n0 * HID + fq] = ao0;
    }
    if (n1 < N) {
        __half2 pa = __floats2half2_rn(ar1.x, ar1.y);
        __half2 pb = __floats2half2_rn(ar1.z, ar1.w);
        uint2 pk; pk.x = *(unsigned*)&pa; pk.y = *(unsigned*)&pb;
        *(uint2*)&A[(size_t)n1 * HID + fq] = pk;
        ao1.x += bb.x; ao1.y += bb.y; ao1.z += bb.z; ao1.w += bb.w;
        *(float4*)&C[(size_t)n1 * HID + fq] = ao1;
    }
}

// ---------- rest of the deterministic partition build ----------

__global__ __launch_bounds__(256) void bucket_scan(
    int* __restrict__ cbb, int* __restrict__ btot, int NBLK)
{
    __shared__ int sc[256];
    size_t row = (size_t)blockIdx.x * NBLK;
    int t = threadIdx.x;
    int base = t * 4;
    int v[4]; int s = 0;
    #pragma unroll
    for (int j = 0; j < 4; ++j) { v[j] = (base + j < NBLK) ? cbb[row + base + j] : 0; s += v[j]; }
    sc[t] = s;
    __syncthreads();
    int acc = s;
    for (int off = 1; off < 256; off <<= 1) {
        int add = (t >= off) ? sc[t - off] : 0;
        __syncthreads();
        acc += add;
        sc[t] = acc;
        __syncthreads();
    }
    int run = acc - s;
    #pragma unroll
    for (int j = 0; j < 4; ++j) {
        if (base + j < NBLK) cbb[row + base + j] = run;
        run += v[j];
    }
    if (t == 255) btot[blockIdx.x] = acc;
}

__global__ __launch_bounds__(256) void btot_scan(
    const int* __restrict__ btot, int* __restrict__ bbase, int K)
{
    __shared__ int sc[256];
    int t = threadIdx.x;
    int base = t * 4;
    int v[4]; int s = 0;
    #pragma unroll
    for (int j = 0; j < 4; ++j) { v[j] = (base + j < K) ? btot[base + j] : 0; s += v[j]; }
    sc[t] = s;
    __syncthreads();
    int acc = s;
    for (int off = 1; off < 256; off <<= 1) {
        int add = (t >= off) ? sc[t - off] : 0;
        __syncthreads();
        acc += add;
        sc[t] = acc;
        __syncthreads();
    }
    int run = acc - s;
    #pragma unroll
    for (int j = 0; j < 4; ++j) {
        if (base + j < K) bbase[base + j] = run;
        run += v[j];
    }
    if (t == 255) bbase[K] = acc;
}

// partition: 4096 edges/block, 512 threads; pay = {meta, ew} + 16-bit bucket id;
// global target recomputed at write time (gb[b] + i - lofs[b]) -> 47 KB LDS
__global__ __launch_bounds__(512) void partB(
    const int* __restrict__ src, const int* __restrict__ dst,
    const float* __restrict__ ew, const int* __restrict__ cbb,
    const int* __restrict__ bbase, int2* __restrict__ stg8,
    int E, int K, int NBLK)
{
    __shared__ int2 pay[EPB];               // 32 KB
    __shared__ unsigned short bid[EPB];     // 8 KB
    __shared__ int h[KMAX2];
    __shared__ int lofs[KMAX2];
    __shared__ int gb[KMAX2];
    __shared__ int sc[512];
    int tid = threadIdx.x;
    for (int i = tid; i < K; i += 512) h[i] = 0;
    __syncthreads();

    int base = blockIdx.x * EPB;
    int es[8], ds[8]; float wsr[8];
    #pragma unroll
    for (int k = 0; k < 8; ++k) {
        int e = base + k * 512 + tid;
        if (e < E) {
            es[k] = src[e]; ds[k] = dst[e]; wsr[k] = ew[e];
            atomicAdd(&h[ds[k] >> NB_SHIFT], 1);
        } else ds[k] = -1;
    }
    __syncthreads();

    // block-scan hist: thread t owns bucket t (K <= 512)
    int v0 = (tid < K) ? h[tid] : 0;
    sc[tid] = v0;
    __syncthreads();
    int acc = v0;
    for (int off = 1; off < 512; off <<= 1) {
        int add = (tid >= off) ? sc[tid - off] : 0;
        __syncthreads();
        acc += add;
        sc[tid] = acc;
        __syncthreads();
    }
    if (tid < K) lofs[tid] = acc - v0;
    __syncthreads();

    for (int b = tid; b < K; b += 512) {
        gb[b] = bbase[b] + cbb[(size_t)b * NBLK + blockIdx.x];
        h[b] = lofs[b];
    }
    __syncthreads();

    #pragma unroll
    for (int k = 0; k < 8; ++k) {
        if (ds[k] >= 0) {
            int b = ds[k] >> NB_SHIFT;
            int dloc = ds[k] & (NB_NODES - 1);
            int slot = atomicAdd(&h[b], 1);
            pay[slot] = make_int2(es[k] | (dloc << 17), __float_as_int(wsr[k]));
            bid[slot] = (unsigned short)b;
        }
    }
    __syncthreads();

    int tot = E - base; if (tot > EPB) tot = EPB;
    for (int i = tid; i < tot; i += 512) {
        int b = bid[i];
        stg8[gb[b] + i - lofs[b]] = pay[i];
    }
}

// per bucket: counting-sort edges by dst node, LDS-staged single-pass
__global__ __launch_bounds__(512) void partC2(
    const int2* __restrict__ stg8, const int* __restrict__ bbase,
    int* __restrict__ rowptr, int2* __restrict__ perm, int N, int K)
{
    __shared__ int2 pe[PCAP];          // 47 KB edge staging
    __shared__ int hcnt[NB_NODES];
    __shared__ int hinc[NB_NODES];
    int b = blockIdx.x;
    int n0 = b << NB_SHIFT;
    int nTop = n0 + NB_NODES; if (nTop > N) nTop = N;
    int nloc = nTop - n0;
    int tid = threadIdx.x;
    if (tid < NB_NODES) hcnt[tid] = 0;
    int lo = bbase[b], hi = bbase[b + 1];
    int sz = hi - lo;
    bool fit = (sz <= PCAP);
    if (fit) {
        for (int i = tid; i < sz; i += 512) pe[i] = stg8[lo + i];
    }
    __syncthreads();
    if (fit) {
        for (int i = tid; i < sz; i += 512)
            atomicAdd(&hcnt[pe[i].x >> 17], 1);
    } else {
        for (int e = lo + tid; e < hi; e += 512)
            atomicAdd(&hcnt[stg8[e].x >> 17], 1);
    }
    __syncthreads();
    if (tid < NB_NODES) hinc[tid] = hcnt[tid];
    __syncthreads();
    for (int off = 1; off < NB_NODES; off <<= 1) {
        int v = (tid < NB_NODES && tid >= off) ? hinc[tid - off] : 0;
        __syncthreads();
        if (tid < NB_NODES) hinc[tid] += v;
        __syncthreads();
    }
    if (tid < nloc) {
        int excl = hinc[tid] - hcnt[tid];
        rowptr[n0 + tid] = lo + excl;
        hcnt[tid] = excl;               // reuse as cursor
    }
    if (b == K - 1 && tid == 0) rowptr[N] = hi;
    __syncthreads();
    if (fit) {
        for (int i = tid; i < sz; i += 512) {
            int2 p = pe[i];
            int pos = lo + atomicAdd(&hcnt[p.x >> 17], 1);
            perm[pos] = make_int2(p.x & 0x1FFFF, p.y);
        }
    } else {
        for (int e = lo + tid; e < hi; e += 512) {
            int2 p = stg8[e];
            int pos = lo + atomicAdd(&hcnt[p.x >> 17], 1);
            perm[pos] = make_int2(p.x & 0x1FFFF, p.y);
        }
    }
}

// ---------- gather-side aggregation: 4 lanes per node, no cross-lane reduce ----
__global__ __launch_bounds__(256) void csr_agg(
    const int* __restrict__ rowptr, const int2* __restrict__ perm,
    const __half* __restrict__ A, float* __restrict__ out, int N)
{
    int gid = blockIdx.x * 256 + threadIdx.x;
    int n = gid >> 2;            // 4 threads per node
    if (n >= N) return;
    int q = threadIdx.x & 3;     // uint4 column within 32-half row
    int e0 = rowptr[n], e1 = rowptr[n + 1];
    const uint4* A4 = (const uint4*)A;   // row stride = 4 uint4
    float a0[8] = {0.f,0.f,0.f,0.f,0.f,0.f,0.f,0.f};
    float a1[8] = {0.f,0.f,0.f,0.f,0.f,0.f,0.f,0.f};
    int e = e0;
    for (; e + 1 < e1; e += 2) {
        int2 p0 = perm[e];
        int2 p1 = perm[e + 1];
        uint4 r0 = A4[(size_t)p0.x * 4 + q];
        uint4 r1 = A4[(size_t)p1.x * 4 + q];
        float w0 = __int_as_float(p0.y), w1 = __int_as_float(p1.y);
        float2 c0 = __half22float2(*(__half2*)&r0.x);
        float2 c1 = __half22float2(*(__half2*)&r0.y);
        float2 c2 = __half22float2(*(__half2*)&r0.z);
        float2 c3 = __half22float2(*(__half2*)&r0.w);
        a0[0] = fmaf(c0.x, w0, a0[0]); a0[1] = fmaf(c0.y, w0, a0[1]);
        a0[2] = fmaf(c1.x, w0, a0[2]); a0[3] = fmaf(c1.y, w0, a0[3]);
        a0[4] = fmaf(c2.x, w0, a0[4]); a0[5] = fmaf(c2.y, w0, a0[5]);
        a0[6] = fmaf(c3.x, w0, a0[6]); a0[7] = fmaf(c3.y, w0, a0[7]);
        float2 d0 = __half22float2(*(__half2*)&r1.x);
        float2 d1 = __half22float2(*(__half2*)&r1.y);
        float2 d2 = __half22float2(*(__half2*)&r1.z);
        float2 d3 = __half22float2(*(__half2*)&r1.w);
        a1[0] = fmaf(d0.x, w1, a1[0]); a1[1] = fmaf(d0.y, w1, a1[1]);
        a1[2] = fmaf(d1.x, w1, a1[2]); a1[3] = fmaf(d1.y, w1, a1[3]);
        a1[4] = fmaf(d2.x, w1, a1[4]); a1[5] = fmaf(d2.y, w1, a1[5]);
        a1[6] = fmaf(d3.x, w1, a1[6]); a1[7] = fmaf(d3.y, w1, a1[7]);
    }
    if (e < e1) {
        int2 p = perm[e];
        uint4 r = A4[(size_t)p.x * 4 + q];
        float w = __int_as_float(p.y);
        float2 c0 = __half22float2(*(__half2*)&r.x);
        float2 c1 = __half22float2(*(__half2*)&r.y);
        float2 c2 = __half22float2(*(__half2*)&r.z);
        float2 c3 = __half22float2(*(__half2*)&r.w);
        a0[0] = fmaf(c0.x, w, a0[0]); a0[1] = fmaf(c0.y, w, a0[1]);
        a0[2] = fmaf(c1.x, w, a0[2]); a0[3] = fmaf(c1.y, w, a0[3]);
        a0[4] = fmaf(c2.x, w, a0[4]); a0[5] = fmaf(c2.y, w, a0[5]);
        a0[6] = fmaf(c3.x, w, a0[6]); a0[7] = fmaf(c3.y, w, a0[7]);
    }
    #pragma unroll
    for (int i = 0; i < 8; ++i) a0[i] += a1[i];
    float4* O4 = (float4*)out;
    size_t oi = (size_t)n * 8 + q * 2;
    float4 o = O4[oi];
    o.x += a0[0]; o.y += a0[1]; o.z += a0[2]; o.w += a0[3];
    O4[oi] = o;
    float4 p = O4[oi + 1];
    p.x += a0[4]; p.y += a0[5]; p.z += a0[6]; p.w += a0[7];
    O4[oi + 1] = p;
}

// ---------- fused pool + MLP: one block per graph, batch sorted ----------
__global__ __launch_bounds__(256) void pool_mlp(
    const float* __restrict__ C, const int* __restrict__ batch, int N,
    const float* __restrict__ W1, const float* __restrict__ b1,
    const float* __restrict__ W2, const float* __restrict__ b2,
    const float* __restrict__ W3, const float* __restrict__ b3,
    float* __restrict__ out)
{
    int g = blockIdx.x;
    int tid = threadIdx.x;
    int lo, hi;
    {
        int l = 0, r = N;
        while (l < r) { int m = (l + r) >> 1; if (batch[m] < g) l = m + 1; else r = m; }
        lo = l;
        r = N;
        while (l < r) { int m = (l + r) >> 1; if (batch[m] < g + 1) l = m + 1; else r = m; }
        hi = l;
    }
    __shared__ float ssum[8][32];
    __shared__ float gvec[32];
    __shared__ float h1v[32];
    __shared__ float h2v[16];
    int f = tid & 31, seg = tid >> 5;
    float acc = 0.f;
    for (int n = lo + seg; n < hi; n += 8) {
        float v = C[(size_t)n * HID + f];
        acc += v > 0.f ? v : 0.f;
    }
    ssum[seg][f] = acc;
    __syncthreads();
    if (tid < 32) {
        float s = 0.f;
        #pragma unroll
        for (int k = 0; k < 8; ++k) s += ssum[k][tid];
        float c = (float)(hi - lo); c = c > 1.f ? c : 1.f;
        gvec[tid] = s / c;
    }
    __syncthreads();
    if (tid < 32) {
        float a = b1[tid];
        #pragma unroll
        for (int k = 0; k < 32; ++k) a = fmaf(gvec[k], W1[k * 32 + tid], a);
        h1v[tid] = a > 0.f ? a : 0.f;
    }
    __syncthreads();
    if (tid < 16) {
        float a = b2[tid];
        #pragma unroll
        for (int k = 0; k < 32; ++k) a = fmaf(h1v[k], W2[k * 16 + tid], a);
        h2v[tid] = a > 0.f ? a : 0.f;
    }
    __syncthreads();
    if (tid == 0) {
        float o = b3[0];
        #pragma unroll
        for (int k = 0; k < 16; ++k) o = fmaf(h2v[k], W3[k], o);
        out[g] = o;
    }
}

extern "C" void kernel_launch(void* const* d_in, const int* in_sizes, int n_in,
                              void* d_out, int out_size, void* d_ws, size_t ws_size,
                              hipStream_t stream) {
    const float* x     = (const float*)d_in[0];
    const int*   ei    = (const int*)d_in[1];
    const float* ew    = (const float*)d_in[2];
    const int*   batch = (const int*)d_in[3];
    const float* c1rw  = (const float*)d_in[4];
    const float* c1rb  = (const float*)d_in[5];
    const float* c1ow  = (const float*)d_in[6];
    const float* c2rw  = (const float*)d_in[7];
    const float* c2rb  = (const float*)d_in[8];
    const float* c2ow  = (const float*)d_in[9];
    const float* l1w   = (const float*)d_in[10];
    const float* l1b   = (const float*)d_in[11];
    const float* l2w   = (const float*)d_in[12];
    const float* l2b   = (const float*)d_in[13];
    const float* lw    = (const float*)d_in[14];
    const float* lb    = (const float*)d_in[15];

    int N = in_sizes[0] / FIN;      // 100000
    int E = in_sizes[2];            // 1600000
    const int* src = ei;
    const int* dst = ei + E;
    int K    = (N + NB_NODES - 1) >> NB_SHIFT;   // 391 buckets (256 nodes)
    int NBLK = (E + EPB - 1) / EPB;              // 391 edge blocks (4096 each)

    // ---- workspace layout (no aliasing: lin64 runs concurrently with build) ----
    char* ws = (char*)d_ws;
    size_t off = 0;
    auto alloc = [&](size_t nbytes) { void* p = ws + off; off += (nbytes + 255) & ~size_t(255); return p; };
    __half* A      = (__half*)alloc((size_t)N * HID * 2);        // 6.4 MB (fp16)
    float*  BC     = (float*) alloc((size_t)N * HID * 4);        // 12.8 MB
    int2*   perm   = (int2*)  alloc((size_t)E * 8);              // 12.8 MB
    int2*   stg8   = (int2*)  alloc((size_t)E * 8);              // 12.8 MB
    int*    cbb    = (int*)   alloc((size_t)K * NBLK * 4);       // 0.61 MB
    int*    rowptr = (int*)   alloc((size_t)(N + 1) * 4);
    int*    btot   = (int*)   alloc((size_t)KMAX2 * 4);
    int*    bbase  = (int*)   alloc((size_t)(KMAX2 + 1) * 4);

    int nb_node = (N + NT - 1) / NT;
    int nb_agg  = (int)(((long long)N * 4 + 255) / 256);   // 4 threads per node

    // fused: histogram (NBLK blocks) || conv1 linear (nb_node blocks)
    hist_lin64<<<NBLK + nb_node, 256, 0, stream>>>(
        dst, cbb, E, K, NBLK, x, c1rw, c1ow, c1rb, A, BC, N);
    // rest of partition build
    bucket_scan<<<K, 256, 0, stream>>>(cbb, btot, NBLK);
    btot_scan<<<1, 256, 0, stream>>>(btot, bbase, K);
    partB<<<NBLK, 512, 0, stream>>>(src, dst, ew, cbb, bbase, stg8, E, K, NBLK);
    partC2<<<K, 512, 0, stream>>>(stg8, bbase, rowptr, perm, N, K);

    // conv1 aggregation
    csr_agg<<<nb_agg, 256, 0, stream>>>(rowptr, perm, A, BC, N);
    // conv2 (relu fused into node_lin32 load; A overwritten with layer-2 rel-proj)
    node_lin32<<<nb_node, 256, 0, stream>>>(BC, c2rw, c2ow, c2rb, A, BC, N);
    csr_agg<<<nb_agg, 256, 0, stream>>>(rowptr, perm, A, BC, N);
    // fused pool + MLP
    pool_mlp<<<NGRAPH, 256, 0, stream>>>(BC, batch, N, l1w, l1b, l2w, l2b, lw, lb,
                                         (float*)d_out);
}

// Round 21
// 150.799 us; speedup vs baseline: 1.1175x; 1.0195x over previous
//
#include <hip/hip_runtime.h>
#include <hip/hip_fp16.h>

#define NGRAPH 256
#define FIN 64
#define HID 32
#define NB_SHIFT 8            // 256 nodes per bucket
#define NB_NODES 256
#define KMAX2 512
#define EPB 4096              // edges per partition block (hist + partB)
#define NT 64                 // nodes per GEMM block
#define XPAD 68               // 64 + 4 pad (floats): 16B-aligned rows, conflict-free
#define HPAD 36               // 32 + 4 pad
#define PCAP 6016             // partC2 LDS edge-staging capacity

// ---------- fused: bucket_hist (blocks [0,NBLK)) + node_lin64 (rest) ----------
union SU {
    int h[KMAX2];
    struct { float Wr[FIN * HID]; float Wo[FIN * HID]; float b[HID];
             float x[NT * XPAD]; } g;
};

__global__ __launch_bounds__(256, 4) void hist_lin64(
    const int* __restrict__ dst, int* __restrict__ cbb, int E, int K, int NBLK,
    const float* __restrict__ x, const float* __restrict__ Wrel,
    const float* __restrict__ Wroot, const float* __restrict__ bias,
    __half* __restrict__ A, float* __restrict__ B, int N)
{
    __shared__ SU u;
    int tid = threadIdx.x;
    if (blockIdx.x < (unsigned)NBLK) {
        // ---- histogram role: 256 threads x 16 edges ----
        for (int i = tid; i < K; i += 256) u.h[i] = 0;
        __syncthreads();
        int e0 = blockIdx.x * EPB + tid * 16;
        if (e0 + 15 < E) {
            #pragma unroll
            for (int c = 0; c < 4; ++c) {
                int4 d = *reinterpret_cast<const int4*>(dst + e0 + c * 4);
                atomicAdd(&u.h[d.x >> NB_SHIFT], 1);
                atomicAdd(&u.h[d.y >> NB_SHIFT], 1);
                atomicAdd(&u.h[d.z >> NB_SHIFT], 1);
                atomicAdd(&u.h[d.w >> NB_SHIFT], 1);
            }
        } else {
            for (int e = e0; e < E && e < e0 + 16; ++e)
                atomicAdd(&u.h[dst[e] >> NB_SHIFT], 1);
        }
        __syncthreads();
        for (int i = tid; i < K; i += 256)
            cbb[(size_t)i * NBLK + blockIdx.x] = u.h[i];
        return;
    }
    // ---- conv1 linear role ----
    {
        const float4* Wr4 = (const float4*)Wrel;
        const float4* Wo4 = (const float4*)Wroot;
        for (int i = tid; i < FIN * HID / 4; i += 256) {
            ((float4*)u.g.Wr)[i] = Wr4[i];
            ((float4*)u.g.Wo)[i] = Wo4[i];
        }
        if (tid < HID) u.g.b[tid] = bias[tid];
    }
    int base = (blockIdx.x - NBLK) * NT;
    {
        const float4* x4 = (const float4*)x;
        for (int i = tid; i < NT * 16; i += 256) {
            int row = i >> 4, c4 = i & 15;
            int n = base + row;
            float4 v = (n < N) ? x4[(size_t)n * 16 + c4]
                               : make_float4(0.f, 0.f, 0.f, 0.f);
            *(float4*)&u.g.x[row * XPAD + c4 * 4] = v;
        }
    }
    __syncthreads();

    int nl = tid >> 3;          // 0..31
    int fq = (tid & 7) * 4;     // feature quad base
    const float* xa = &u.g.x[nl * XPAD];
    const float* xb = &u.g.x[(nl + 32) * XPAD];
    float4 ar0 = make_float4(0.f,0.f,0.f,0.f), ao0 = ar0;
    float4 ar1 = ar0, ao1 = ar0;
    #pragma unroll 2
    for (int k = 0; k < FIN; k += 4) {
        float4 xa4 = *(const float4*)&xa[k];
        float4 xb4 = *(const float4*)&xb[k];
        #pragma unroll
        for (int j = 0; j < 4; ++j) {
            float4 w4 = *(const float4*)&u.g.Wr[(k + j) * HID + fq];
            float4 o4 = *(const float4*)&u.g.Wo[(k + j) * HID + fq];
            float va = (j == 0) ? xa4.x : (j == 1) ? xa4.y : (j == 2) ? xa4.z : xa4.w;
            float vb = (j == 0) ? xb4.x : (j == 1) ? xb4.y : (j == 2) ? xb4.z : xb4.w;
            ar0.x = fmaf(va, w4.x, ar0.x); ar0.y = fmaf(va, w4.y, ar0.y);
            ar0.z = fmaf(va, w4.z, ar0.z); ar0.w = fmaf(va, w4.w, ar0.w);
            ao0.x = fmaf(va, o4.x, ao0.x); ao0.y = fmaf(va, o4.y, ao0.y);
            ao0.z = fmaf(va, o4.z, ao0.z); ao0.w = fmaf(va, o4.w, ao0.w);
            ar1.x = fmaf(vb, w4.x, ar1.x); ar1.y = fmaf(vb, w4.y, ar1.y);
            ar1.z = fmaf(vb, w4.z, ar1.z); ar1.w = fmaf(vb, w4.w, ar1.w);
            ao1.x = fmaf(vb, o4.x, ao1.x); ao1.y = fmaf(vb, o4.y, ao1.y);
            ao1.z = fmaf(vb, o4.z, ao1.z); ao1.w = fmaf(vb, o4.w, ao1.w);
        }
    }
    float4 bb = *(const float4*)&u.g.b[fq];
    int n0 = base + nl, n1 = base + nl + 32;
    if (n0 < N) {
        __half2 pa = __floats2half2_rn(ar0.x, ar0.y);
        __half2 pb = __floats2half2_rn(ar0.z, ar0.w);
        uint2 pk; pk.x = *(unsigned*)&pa; pk.y = *(unsigned*)&pb;
        *(uint2*)&A[(size_t)n0 * HID + fq] = pk;
        ao0.x += bb.x; ao0.y += bb.y; ao0.z += bb.z; ao0.w += bb.w;
        *(float4*)&B[(size_t)n0 * HID + fq] = ao0;
    }
    if (n1 < N) {
        __half2 pa = __floats2half2_rn(ar1.x, ar1.y);
        __half2 pb = __floats2half2_rn(ar1.z, ar1.w);
        uint2 pk; pk.x = *(unsigned*)&pa; pk.y = *(unsigned*)&pb;
        *(uint2*)&A[(size_t)n1 * HID + fq] = pk;
        ao1.x += bb.x; ao1.y += bb.y; ao1.z += bb.z; ao1.w += bb.w;
        *(float4*)&B[(size_t)n1 * HID + fq] = ao1;
    }
}

// ---------- node GEMM 2: relu fused on load, FIN=32 ----------
__global__ __launch_bounds__(256, 4) void node_lin32(
    const float* __restrict__ Hpre, const float* __restrict__ Wrel,
    const float* __restrict__ Wroot, const float* __restrict__ bias,
    __half* __restrict__ A, float* __restrict__ C, int N)
{
    __shared__ float sWr[HID * HID];      // 4 KB
    __shared__ float sWo[HID * HID];
    __shared__ float sb[HID];
    __shared__ float sh[NT * HPAD];       // 9.2 KB
    int tid = threadIdx.x;
    {
        const float4* Wr4 = (const float4*)Wrel;
        const float4* Wo4 = (const float4*)Wroot;
        for (int i = tid; i < HID * HID / 4; i += 256) {
            ((float4*)sWr)[i] = Wr4[i];
            ((float4*)sWo)[i] = Wo4[i];
        }
        if (tid < HID) sb[tid] = bias[tid];
    }
    int base = blockIdx.x * NT;
    {
        const float4* H4 = (const float4*)Hpre;
        for (int i = tid; i < NT * 8; i += 256) {
            int row = i >> 3, c4 = i & 7;
            int n = base + row;
            float4 v = make_float4(0.f, 0.f, 0.f, 0.f);
            if (n < N) {
                v = H4[(size_t)n * 8 + c4];
                v.x = v.x > 0.f ? v.x : 0.f; v.y = v.y > 0.f ? v.y : 0.f;
                v.z = v.z > 0.f ? v.z : 0.f; v.w = v.w > 0.f ? v.w : 0.f;
            }
            *(float4*)&sh[row * HPAD + c4 * 4] = v;
        }
    }
    __syncthreads();

    int nl = tid >> 3;
    int fq = (tid & 7) * 4;
    const float* xa = &sh[nl * HPAD];
    const float* xb = &sh[(nl + 32) * HPAD];
    float4 ar0 = make_float4(0.f,0.f,0.f,0.f), ao0 = ar0;
    float4 ar1 = ar0, ao1 = ar0;
    #pragma unroll 2
    for (int k = 0; k < HID; k += 4) {
        float4 xa4 = *(const float4*)&xa[k];
        float4 xb4 = *(const float4*)&xb[k];
        #pragma unroll
        for (int j = 0; j < 4; ++j) {
            float4 w4 = *(const float4*)&sWr[(k + j) * HID + fq];
            float4 o4 = *(const float4*)&sWo[(k + j) * HID + fq];
            float va = (j == 0) ? xa4.x : (j == 1) ? xa4.y : (j == 2) ? xa4.z : xa4.w;
            float vb = (j == 0) ? xb4.x : (j == 1) ? xb4.y : (j == 2) ? xb4.z : xb4.w;
            ar0.x = fmaf(va, w4.x, ar0.x); ar0.y = fmaf(va, w4.y, ar0.y);
            ar0.z = fmaf(va, w4.z, ar0.z); ar0.w = fmaf(va, w4.w, ar0.w);
            ao0.x = fmaf(va, o4.x, ao0.x); ao0.y = fmaf(va, o4.y, ao0.y);
            ao0.z = fmaf(va, o4.z, ao0.z); ao0.w = fmaf(va, o4.w, ao0.w);
            ar1.x = fmaf(vb, w4.x, ar1.x); ar1.y = fmaf(vb, w4.y, ar1.y);
            ar1.z = fmaf(vb, w4.z, ar1.z); ar1.w = fmaf(vb, w4.w, ar1.w);
            ao1.x = fmaf(vb, o4.x, ao1.x); ao1.y = fmaf(vb, o4.y, ao1.y);
            ao1.z = fmaf(vb, o4.z, ao1.z); ao1.w = fmaf(vb, o4.w, ao1.w);
        }
    }
    float4 bb = *(const float4*)&sb[fq];
    int n0 = base + nl, n1 = base + nl + 32;
    if (n0 < N) {
        __half2 pa = __floats2half2_rn(ar0.x, ar0.y);
        __half2 pb = __floats2half2_rn(ar0.z, ar0.w);
        uint2 pk; pk.x = *(unsigned*)&pa; pk.y = *(unsigned*)&pb;
        *(uint2*)&A[(size_t)n0 * HID + fq] = pk;
        ao0.x += bb.x; ao0.y += bb.y; ao0.z += bb.z; ao0.w += bb.w;
        *(float4*)&C[(size_t)n0 * HID + fq] = ao0;
    }
    if (n1 < N) {
        __half2 pa = __floats2half2_rn(ar1.x, ar1.y);
        __half2 pb = __floats2half2_rn(ar1.z, ar1.w);
        uint2 pk; pk.x = *(unsigned*)&pa; pk.y = *(unsigned*)&pb;
        *(uint2*)&A[(size_t)n1 * HID + fq] = pk;
        ao1.x += bb.x; ao1.y += bb.y; ao1.z += bb.z; ao1.w += bb.w;
        *(float4*)&C[(size_t)n1 * HID + fq] = ao1;
    }
}

// ---------- bucket_scan: per-bucket exclusive scan of cbb rows -> btot ----------
__global__ __launch_bounds__(256) void bucket_scan(
    int* __restrict__ cbb, int* __restrict__ btot, int NBLK)
{
    __shared__ int sc[256];
    size_t row = (size_t)blockIdx.x * NBLK;
    int t = threadIdx.x;
    int base = t * 4;
    int v[4]; int s = 0;
    #pragma unroll
    for (int j = 0; j < 4; ++j) { v[j] = (base + j < NBLK) ? cbb[row + base + j] : 0; s += v[j]; }
    sc[t] = s;
    __syncthreads();
    int acc = s;
    for (int off = 1; off < 256; off <<= 1) {
        int add = (t >= off) ? sc[t - off] : 0;
        __syncthreads();
        acc += add;
        sc[t] = acc;
        __syncthreads();
    }
    int run = acc - s;
    #pragma unroll
    for (int j = 0; j < 4; ++j) {
        if (base + j < NBLK) cbb[row + base + j] = run;
        run += v[j];
    }
    if (t == 255) btot[blockIdx.x] = acc;
}

// partition: 4096 edges/block, 512 threads.  Scans btot in LDS itself (each
// block needs the full bbase vector anyway); block 0 publishes bbase globally.
__global__ __launch_bounds__(512) void partB(
    const int* __restrict__ src, const int* __restrict__ dst,
    const float* __restrict__ ew, const int* __restrict__ cbb,
    const int* __restrict__ btot, int* __restrict__ bbase,
    int2* __restrict__ stg8, int E, int K, int NBLK)
{
    __shared__ int2 pay[EPB];               // 32 KB
    __shared__ unsigned short bid[EPB];     // 8 KB
    __shared__ int h[KMAX2];
    __shared__ int lofs[KMAX2];
    __shared__ int gb[KMAX2];
    __shared__ int sbase[KMAX2];
    __shared__ int sc[512];
    int tid = threadIdx.x;
    for (int i = tid; i < K; i += 512) h[i] = 0;

    // ---- LDS scan of btot -> sbase (exclusive); block 0 publishes globally ----
    int bv = (tid < K) ? btot[tid] : 0;
    sc[tid] = bv;
    __syncthreads();
    int bacc = bv;
    for (int off = 1; off < 512; off <<= 1) {
        int add = (tid >= off) ? sc[tid - off] : 0;
        __syncthreads();
        bacc += add;
        sc[tid] = bacc;
        __syncthreads();
    }
    if (tid < K) sbase[tid] = bacc - bv;
    if (blockIdx.x == 0) {
        if (tid < K) bbase[tid] = bacc - bv;
        if (tid == K - 1) bbase[K] = bacc;     // = E
    }
    __syncthreads();

    int base = blockIdx.x * EPB;
    int es[8], ds[8]; float wsr[8];
    #pragma unroll
    for (int k = 0; k < 8; ++k) {
        int e = base + k * 512 + tid;
        if (e < E) {
            es[k] = src[e]; ds[k] = dst[e]; wsr[k] = ew[e];
            atomicAdd(&h[ds[k] >> NB_SHIFT], 1);
        } else ds[k] = -1;
    }
    __syncthreads();

    // block-scan hist: thread t owns bucket t (K <= 512)
    int v0 = (tid < K) ? h[tid] : 0;
    sc[tid] = v0;
    __syncthreads();
    int acc = v0;
    for (int off = 1; off < 512; off <<= 1) {
        int add = (tid >= off) ? sc[tid - off] : 0;
        __syncthreads();
        acc += add;
        sc[tid] = acc;
        __syncthreads();
    }
    if (tid < K) lofs[tid] = acc - v0;
    __syncthreads();

    for (int b = tid; b < K; b += 512) {
        gb[b] = sbase[b] + cbb[(size_t)b * NBLK + blockIdx.x];
        h[b] = lofs[b];
    }
    __syncthreads();

    #pragma unroll
    for (int k = 0; k < 8; ++k) {
        if (ds[k] >= 0) {
            int b = ds[k] >> NB_SHIFT;
            int dloc = ds[k] & (NB_NODES - 1);
            int slot = atomicAdd(&h[b], 1);
            pay[slot] = make_int2(es[k] | (dloc << 17), __float_as_int(wsr[k]));
            bid[slot] = (unsigned short)b;
        }
    }
    __syncthreads();

    int tot = E - base; if (tot > EPB) tot = EPB;
    for (int i = tid; i < tot; i += 512) {
        int b = bid[i];
        stg8[gb[b] + i - lofs[b]] = pay[i];
    }
}

// per bucket: counting-sort edges by dst node, LDS-staged single-pass
__global__ __launch_bounds__(512) void partC2(
    const int2* __restrict__ stg8, const int* __restrict__ bbase,
    int* __restrict__ rowptr, int2* __restrict__ perm, int N, int K)
{
    __shared__ int2 pe[PCAP];          // 47 KB edge staging
    __shared__ int hcnt[NB_NODES];
    __shared__ int hinc[NB_NODES];
    int b = blockIdx.x;
    int n0 = b << NB_SHIFT;
    int nTop = n0 + NB_NODES; if (nTop > N) nTop = N;
    int nloc = nTop - n0;
    int tid = threadIdx.x;
    if (tid < NB_NODES) hcnt[tid] = 0;
    int lo = bbase[b], hi = bbase[b + 1];
    int sz = hi - lo;
    bool fit = (sz <= PCAP);
    if (fit) {
        for (int i = tid; i < sz; i += 512) pe[i] = stg8[lo + i];
    }
    __syncthreads();
    if (fit) {
        for (int i = tid; i < sz; i += 512)
            atomicAdd(&hcnt[pe[i].x >> 17], 1);
    } else {
        for (int e = lo + tid; e < hi; e += 512)
            atomicAdd(&hcnt[stg8[e].x >> 17], 1);
    }
    __syncthreads();
    if (tid < NB_NODES) hinc[tid] = hcnt[tid];
    __syncthreads();
    for (int off = 1; off < NB_NODES; off <<= 1) {
        int v = (tid < NB_NODES && tid >= off) ? hinc[tid - off] : 0;
        __syncthreads();
        if (tid < NB_NODES) hinc[tid] += v;
        __syncthreads();
    }
    if (tid < nloc) {
        int excl = hinc[tid] - hcnt[tid];
        rowptr[n0 + tid] = lo + excl;
        hcnt[tid] = excl;               // reuse as cursor
    }
    if (b == K - 1 && tid == 0) rowptr[N] = hi;
    __syncthreads();
    if (fit) {
        for (int i = tid; i < sz; i += 512) {
            int2 p = pe[i];
            int pos = lo + atomicAdd(&hcnt[p.x >> 17], 1);
            perm[pos] = make_int2(p.x & 0x1FFFF, p.y);
        }
    } else {
        for (int e = lo + tid; e < hi; e += 512) {
            int2 p = stg8[e];
            int pos = lo + atomicAdd(&hcnt[p.x >> 17], 1);
            perm[pos] = make_int2(p.x & 0x1FFFF, p.y);
        }
    }
}

// ---------- gather-side aggregation: 4 lanes per node, no cross-lane reduce ----
__global__ __launch_bounds__(256) void csr_agg(
    const int* __restrict__ rowptr, const int2* __restrict__ perm,
    const __half* __restrict__ A, float* __restrict__ out, int N)
{
    int gid = blockIdx.x * 256 + threadIdx.x;
    int n = gid >> 2;            // 4 threads per node
    if (n >= N) return;
    int q = threadIdx.x & 3;     // uint4 column within 32-half row
    int e0 = rowptr[n], e1 = rowptr[n + 1];
    const uint4* A4 = (const uint4*)A;   // row stride = 4 uint4
    float a0[8] = {0.f,0.f,0.f,0.f,0.f,0.f,0.f,0.f};
    float a1[8] = {0.f,0.f,0.f,0.f,0.f,0.f,0.f,0.f};
    int e = e0;
    for (; e + 1 < e1; e += 2) {
        int2 p0 = perm[e];
        int2 p1 = perm[e + 1];
        uint4 r0 = A4[(size_t)p0.x * 4 + q];
        uint4 r1 = A4[(size_t)p1.x * 4 + q];
        float w0 = __int_as_float(p0.y), w1 = __int_as_float(p1.y);
        float2 c0 = __half22float2(*(__half2*)&r0.x);
        float2 c1 = __half22float2(*(__half2*)&r0.y);
        float2 c2 = __half22float2(*(__half2*)&r0.z);
        float2 c3 = __half22float2(*(__half2*)&r0.w);
        a0[0] = fmaf(c0.x, w0, a0[0]); a0[1] = fmaf(c0.y, w0, a0[1]);
        a0[2] = fmaf(c1.x, w0, a0[2]); a0[3] = fmaf(c1.y, w0, a0[3]);
        a0[4] = fmaf(c2.x, w0, a0[4]); a0[5] = fmaf(c2.y, w0, a0[5]);
        a0[6] = fmaf(c3.x, w0, a0[6]); a0[7] = fmaf(c3.y, w0, a0[7]);
        float2 d0 = __half22float2(*(__half2*)&r1.x);
        float2 d1 = __half22float2(*(__half2*)&r1.y);
        float2 d2 = __half22float2(*(__half2*)&r1.z);
        float2 d3 = __half22float2(*(__half2*)&r1.w);
        a1[0] = fmaf(d0.x, w1, a1[0]); a1[1] = fmaf(d0.y, w1, a1[1]);
        a1[2] = fmaf(d1.x, w1, a1[2]); a1[3] = fmaf(d1.y, w1, a1[3]);
        a1[4] = fmaf(d2.x, w1, a1[4]); a1[5] = fmaf(d2.y, w1, a1[5]);
        a1[6] = fmaf(d3.x, w1, a1[6]); a1[7] = fmaf(d3.y, w1, a1[7]);
    }
    if (e < e1) {
        int2 p = perm[e];
        uint4 r = A4[(size_t)p.x * 4 + q];
        float w = __int_as_float(p.y);
        float2 c0 = __half22float2(*(__half2*)&r.x);
        float2 c1 = __half22float2(*(__half2*)&r.y);
        float2 c2 = __half22float2(*(__half2*)&r.z);
        float2 c3 = __half22float2(*(__half2*)&r.w);
        a0[0] = fmaf(c0.x, w, a0[0]); a0[1] = fmaf(c0.y, w, a0[1]);
        a0[2] = fmaf(c1.x, w, a0[2]); a0[3] = fmaf(c1.y, w, a0[3]);
        a0[4] = fmaf(c2.x, w, a0[4]); a0[5] = fmaf(c2.y, w, a0[5]);
        a0[6] = fmaf(c3.x, w, a0[6]); a0[7] = fmaf(c3.y, w, a0[7]);
    }
    #pragma unroll
    for (int i = 0; i < 8; ++i) a0[i] += a1[i];
    float4* O4 = (float4*)out;
    size_t oi = (size_t)n * 8 + q * 2;
    float4 o = O4[oi];
    o.x += a0[0]; o.y += a0[1]; o.z += a0[2]; o.w += a0[3];
    O4[oi] = o;
    float4 p = O4[oi + 1];
    p.x += a0[4]; p.y += a0[5]; p.z += a0[6]; p.w += a0[7];
    O4[oi + 1] = p;
}

// ---------- fused pool + MLP: one block per graph, batch sorted ----------
__global__ __launch_bounds__(256) void pool_mlp(
    const float* __restrict__ C, const int* __restrict__ batch, int N,
    const float* __restrict__ W1, const float* __restrict__ b1,
    const float* __restrict__ W2, const float* __restrict__ b2,
    const float* __restrict__ W3, const float* __restrict__ b3,
    float* __restrict__ out)
{
    int g = blockIdx.x;
    int tid = threadIdx.x;
    int lo, hi;
    {
        int l = 0, r = N;
        while (l < r) { int m = (l + r) >> 1; if (batch[m] < g) l = m + 1; else r = m; }
        lo = l;
        r = N;
        while (l < r) { int m = (l + r) >> 1; if (batch[m] < g + 1) l = m + 1; else r = m; }
        hi = l;
    }
    __shared__ float ssum[8][32];
    __shared__ float gvec[32];
    __shared__ float h1v[32];
    __shared__ float h2v[16];
    int f = tid & 31, seg = tid >> 5;
    float acc = 0.f;
    for (int n = lo + seg; n < hi; n += 8) {
        float v = C[(size_t)n * HID + f];
        acc += v > 0.f ? v : 0.f;
    }
    ssum[seg][f] = acc;
    __syncthreads();
    if (tid < 32) {
        float s = 0.f;
        #pragma unroll
        for (int k = 0; k < 8; ++k) s += ssum[k][tid];
        float c = (float)(hi - lo); c = c > 1.f ? c : 1.f;
        gvec[tid] = s / c;
    }
    __syncthreads();
    if (tid < 32) {
        float a = b1[tid];
        #pragma unroll
        for (int k = 0; k < 32; ++k) a = fmaf(gvec[k], W1[k * 32 + tid], a);
        h1v[tid] = a > 0.f ? a : 0.f;
    }
    __syncthreads();
    if (tid < 16) {
        float a = b2[tid];
        #pragma unroll
        for (int k = 0; k < 32; ++k) a = fmaf(h1v[k], W2[k * 16 + tid], a);
        h2v[tid] = a > 0.f ? a : 0.f;
    }
    __syncthreads();
    if (tid == 0) {
        float o = b3[0];
        #pragma unroll
        for (int k = 0; k < 16; ++k) o = fmaf(h2v[k], W3[k], o);
        out[g] = o;
    }
}

extern "C" void kernel_launch(void* const* d_in, const int* in_sizes, int n_in,
                              void* d_out, int out_size, void* d_ws, size_t ws_size,
                              hipStream_t stream) {
    const float* x     = (const float*)d_in[0];
    const int*   ei    = (const int*)d_in[1];
    const float* ew    = (const float*)d_in[2];
    const int*   batch = (const int*)d_in[3];
    const float* c1rw  = (const float*)d_in[4];
    const float* c1rb  = (const float*)d_in[5];
    const float* c1ow  = (const float*)d_in[6];
    const float* c2rw  = (const float*)d_in[7];
    const float* c2rb  = (const float*)d_in[8];
    const float* c2ow  = (const float*)d_in[9];
    const float* l1w   = (const float*)d_in[10];
    const float* l1b   = (const float*)d_in[11];
    const float* l2w   = (const float*)d_in[12];
    const float* l2b   = (const float*)d_in[13];
    const float* lw    = (const float*)d_in[14];
    const float* lb    = (const float*)d_in[15];

    int N = in_sizes[0] / FIN;      // 100000
    int E = in_sizes[2];            // 1600000
    const int* src = ei;
    const int* dst = ei + E;
    int K    = (N + NB_NODES - 1) >> NB_SHIFT;   // 391 buckets (256 nodes)
    int NBLK = (E + EPB - 1) / EPB;              // 391 edge blocks (4096 each)

    // ---- workspace layout (no aliasing: lin64 runs concurrently with build) ----
    char* ws = (char*)d_ws;
    size_t off = 0;
    auto alloc = [&](size_t nbytes) { void* p = ws + off; off += (nbytes + 255) & ~size_t(255); return p; };
    __half* A      = (__half*)alloc((size_t)N * HID * 2);        // 6.4 MB (fp16)
    float*  BC     = (float*) alloc((size_t)N * HID * 4);        // 12.8 MB
    int2*   perm   = (int2*)  alloc((size_t)E * 8);              // 12.8 MB
    int2*   stg8   = (int2*)  alloc((size_t)E * 8);              // 12.8 MB
    int*    cbb    = (int*)   alloc((size_t)K * NBLK * 4);       // 0.61 MB
    int*    rowptr = (int*)   alloc((size_t)(N + 1) * 4);
    int*    btot   = (int*)   alloc((size_t)KMAX2 * 4);
    int*    bbase  = (int*)   alloc((size_t)(KMAX2 + 1) * 4);

    int nb_node = (N + NT - 1) / NT;
    int nb_agg  = (int)(((long long)N * 4 + 255) / 256);   // 4 threads per node

    // fused: histogram (NBLK blocks) || conv1 linear (nb_node blocks)
    hist_lin64<<<NBLK + nb_node, 256, 0, stream>>>(
        dst, cbb, E, K, NBLK, x, c1rw, c1ow, c1rb, A, BC, N);
    // partition build: scan, then partB (absorbs btot scan, publishes bbase)
    bucket_scan<<<K, 256, 0, stream>>>(cbb, btot, NBLK);
    partB<<<NBLK, 512, 0, stream>>>(src, dst, ew, cbb, btot, bbase, stg8, E, K, NBLK);
    partC2<<<K, 512, 0, stream>>>(stg8, bbase, rowptr, perm, N, K);

    // conv1 aggregation
    csr_agg<<<nb_agg, 256, 0, stream>>>(rowptr, perm, A, BC, N);
    // conv2 (relu fused into node_lin32 load; A overwritten with layer-2 rel-proj)
    node_lin32<<<nb_node, 256, 0, stream>>>(BC, c2rw, c2ow, c2rb, A, BC, N);
    csr_agg<<<nb_agg, 256, 0, stream>>>(rowptr, perm, A, BC, N);
    // fused pool + MLP
    pool_mlp<<<NGRAPH, 256, 0, stream>>>(BC, batch, N, l1w, l1b, l2w, l2b, lw, lb,
                                         (float*)d_out);
}

// Round 22
// 150.487 us; speedup vs baseline: 1.1198x; 1.0021x over previous
//
#include <hip/hip_runtime.h>
#include <hip/hip_fp16.h>

#define NGRAPH 256
#define FIN 64
#define HID 32
#define NB_SHIFT 8            // 256 nodes per bucket
#define NB_NODES 256
#define KMAX2 512
#define EPB 4096              // edges per partition block (hist + partB)
#define NT 64                 // nodes per GEMM block
#define XPAD 68               // 64 + 4 pad (floats): 16B-aligned rows
#define HPAD 36               // 32 + 4 pad
#define PCAP 6016             // partC2 LDS edge-staging capacity

// ---------- fused: bucket_hist (blocks [0,NBLK)) + node_lin64 (rest) ----------
union SU {
    int h[KMAX2];
    struct { float Wr[FIN * HID]; float Wo[FIN * HID]; float b[HID];
             float x[NT * XPAD]; } g;
};

__global__ __launch_bounds__(256, 4) void hist_lin64(
    const int* __restrict__ dst, int* __restrict__ cbb, int E, int K, int NBLK,
    const float* __restrict__ x, const float* __restrict__ Wrel,
    const float* __restrict__ Wroot, const float* __restrict__ bias,
    __half* __restrict__ A, float* __restrict__ B, int N)
{
    __shared__ SU u;
    int tid = threadIdx.x;
    if (blockIdx.x < (unsigned)NBLK) {
        // ---- histogram role: 256 threads x 16 edges ----
        for (int i = tid; i < K; i += 256) u.h[i] = 0;
        __syncthreads();
        int e0 = blockIdx.x * EPB + tid * 16;
        if (e0 + 15 < E) {
            #pragma unroll
            for (int c = 0; c < 4; ++c) {
                int4 d = *reinterpret_cast<const int4*>(dst + e0 + c * 4);
                atomicAdd(&u.h[d.x >> NB_SHIFT], 1);
                atomicAdd(&u.h[d.y >> NB_SHIFT], 1);
                atomicAdd(&u.h[d.z >> NB_SHIFT], 1);
                atomicAdd(&u.h[d.w >> NB_SHIFT], 1);
            }
        } else {
            for (int e = e0; e < E && e < e0 + 16; ++e)
                atomicAdd(&u.h[dst[e] >> NB_SHIFT], 1);
        }
        __syncthreads();
        for (int i = tid; i < K; i += 256)
            cbb[(size_t)i * NBLK + blockIdx.x] = u.h[i];
        return;
    }
    // ---- conv1 linear role ----
    {
        const float4* Wr4 = (const float4*)Wrel;
        const float4* Wo4 = (const float4*)Wroot;
        for (int i = tid; i < FIN * HID / 4; i += 256) {
            ((float4*)u.g.Wr)[i] = Wr4[i];
            ((float4*)u.g.Wo)[i] = Wo4[i];
        }
        if (tid < HID) u.g.b[tid] = bias[tid];
    }
    int base = (blockIdx.x - NBLK) * NT;
    {
        const float4* x4 = (const float4*)x;
        for (int i = tid; i < NT * 16; i += 256) {
            int row = i >> 4, c4 = i & 15;
            int n = base + row;
            float4 v = (n < N) ? x4[(size_t)n * 16 + c4]
                               : make_float4(0.f, 0.f, 0.f, 0.f);
            *(float4*)&u.g.x[row * XPAD + c4 * 4] = v;
        }
    }
    __syncthreads();

    int nl = tid >> 3;          // 0..31
    int fq = (tid & 7) * 4;     // feature quad base
    const float* xa = &u.g.x[nl * XPAD];
    const float* xb = &u.g.x[(nl + 32) * XPAD];
    float4 ar0 = make_float4(0.f,0.f,0.f,0.f), ao0 = ar0;
    float4 ar1 = ar0, ao1 = ar0;
    #pragma unroll 2
    for (int k = 0; k < FIN; k += 4) {
        float4 xa4 = *(const float4*)&xa[k];
        float4 xb4 = *(const float4*)&xb[k];
        #pragma unroll
        for (int j = 0; j < 4; ++j) {
            float4 w4 = *(const float4*)&u.g.Wr[(k + j) * HID + fq];
            float4 o4 = *(const float4*)&u.g.Wo[(k + j) * HID + fq];
            float va = (j == 0) ? xa4.x : (j == 1) ? xa4.y : (j == 2) ? xa4.z : xa4.w;
            float vb = (j == 0) ? xb4.x : (j == 1) ? xb4.y : (j == 2) ? xb4.z : xb4.w;
            ar0.x = fmaf(va, w4.x, ar0.x); ar0.y = fmaf(va, w4.y, ar0.y);
            ar0.z = fmaf(va, w4.z, ar0.z); ar0.w = fmaf(va, w4.w, ar0.w);
            ao0.x = fmaf(va, o4.x, ao0.x); ao0.y = fmaf(va, o4.y, ao0.y);
            ao0.z = fmaf(va, o4.z, ao0.z); ao0.w = fmaf(va, o4.w, ao0.w);
            ar1.x = fmaf(vb, w4.x, ar1.x); ar1.y = fmaf(vb, w4.y, ar1.y);
            ar1.z = fmaf(vb, w4.z, ar1.z); ar1.w = fmaf(vb, w4.w, ar1.w);
            ao1.x = fmaf(vb, o4.x, ao1.x); ao1.y = fmaf(vb, o4.y, ao1.y);
            ao1.z = fmaf(vb, o4.z, ao1.z); ao1.w = fmaf(vb, o4.w, ao1.w);
        }
    }
    float4 bb = *(const float4*)&u.g.b[fq];
    int n0 = base + nl, n1 = base + nl + 32;
    if (n0 < N) {
        __half2 pa = __floats2half2_rn(ar0.x, ar0.y);
        __half2 pb = __floats2half2_rn(ar0.z, ar0.w);
        uint2 pk; pk.x = *(unsigned*)&pa; pk.y = *(unsigned*)&pb;
        *(uint2*)&A[(size_t)n0 * HID + fq] = pk;
        ao0.x += bb.x; ao0.y += bb.y; ao0.z += bb.z; ao0.w += bb.w;
        *(float4*)&B[(size_t)n0 * HID + fq] = ao0;
    }
    if (n1 < N) {
        __half2 pa = __floats2half2_rn(ar1.x, ar1.y);
        __half2 pb = __floats2half2_rn(ar1.z, ar1.w);
        uint2 pk; pk.x = *(unsigned*)&pa; pk.y = *(unsigned*)&pb;
        *(uint2*)&A[(size_t)n1 * HID + fq] = pk;
        ao1.x += bb.x; ao1.y += bb.y; ao1.z += bb.z; ao1.w += bb.w;
        *(float4*)&B[(size_t)n1 * HID + fq] = ao1;
    }
}

// ---------- node GEMM 2: relu fused on load, FIN=32 ----------
__global__ __launch_bounds__(256, 4) void node_lin32(
    const float* __restrict__ Hpre, const float* __restrict__ Wrel,
    const float* __restrict__ Wroot, const float* __restrict__ bias,
    __half* __restrict__ A, float* __restrict__ C, int N)
{
    __shared__ float sWr[HID * HID];      // 4 KB
    __shared__ float sWo[HID * HID];
    __shared__ float sb[HID];
    __shared__ float sh[NT * HPAD];       // 9.2 KB
    int tid = threadIdx.x;
    {
        const float4* Wr4 = (const float4*)Wrel;
        const float4* Wo4 = (const float4*)Wroot;
        for (int i = tid; i < HID * HID / 4; i += 256) {
            ((float4*)sWr)[i] = Wr4[i];
            ((float4*)sWo)[i] = Wo4[i];
        }
        if (tid < HID) sb[tid] = bias[tid];
    }
    int base = blockIdx.x * NT;
    {
        const float4* H4 = (const float4*)Hpre;
        for (int i = tid; i < NT * 8; i += 256) {
            int row = i >> 3, c4 = i & 7;
            int n = base + row;
            float4 v = make_float4(0.f, 0.f, 0.f, 0.f);
            if (n < N) {
                v = H4[(size_t)n * 8 + c4];
                v.x = v.x > 0.f ? v.x : 0.f; v.y = v.y > 0.f ? v.y : 0.f;
                v.z = v.z > 0.f ? v.z : 0.f; v.w = v.w > 0.f ? v.w : 0.f;
            }
            *(float4*)&sh[row * HPAD + c4 * 4] = v;
        }
    }
    __syncthreads();

    int nl = tid >> 3;
    int fq = (tid & 7) * 4;
    const float* xa = &sh[nl * HPAD];
    const float* xb = &sh[(nl + 32) * HPAD];
    float4 ar0 = make_float4(0.f,0.f,0.f,0.f), ao0 = ar0;
    float4 ar1 = ar0, ao1 = ar0;
    #pragma unroll 2
    for (int k = 0; k < HID; k += 4) {
        float4 xa4 = *(const float4*)&xa[k];
        float4 xb4 = *(const float4*)&xb[k];
        #pragma unroll
        for (int j = 0; j < 4; ++j) {
            float4 w4 = *(const float4*)&sWr[(k + j) * HID + fq];
            float4 o4 = *(const float4*)&sWo[(k + j) * HID + fq];
            float va = (j == 0) ? xa4.x : (j == 1) ? xa4.y : (j == 2) ? xa4.z : xa4.w;
            float vb = (j == 0) ? xb4.x : (j == 1) ? xb4.y : (j == 2) ? xb4.z : xb4.w;
            ar0.x = fmaf(va, w4.x, ar0.x); ar0.y = fmaf(va, w4.y, ar0.y);
            ar0.z = fmaf(va, w4.z, ar0.z); ar0.w = fmaf(va, w4.w, ar0.w);
            ao0.x = fmaf(va, o4.x, ao0.x); ao0.y = fmaf(va, o4.y, ao0.y);
            ao0.z = fmaf(va, o4.z, ao0.z); ao0.w = fmaf(va, o4.w, ao0.w);
            ar1.x = fmaf(vb, w4.x, ar1.x); ar1.y = fmaf(vb, w4.y, ar1.y);
            ar1.z = fmaf(vb, w4.z, ar1.z); ar1.w = fmaf(vb, w4.w, ar1.w);
            ao1.x = fmaf(vb, o4.x, ao1.x); ao1.y = fmaf(vb, o4.y, ao1.y);
            ao1.z = fmaf(vb, o4.z, ao1.z); ao1.w = fmaf(vb, o4.w, ao1.w);
        }
    }
    float4 bb = *(const float4*)&sb[fq];
    int n0 = base + nl, n1 = base + nl + 32;
    if (n0 < N) {
        __half2 pa = __floats2half2_rn(ar0.x, ar0.y);
        __half2 pb = __floats2half2_rn(ar0.z, ar0.w);
        uint2 pk; pk.x = *(unsigned*)&pa; pk.y = *(unsigned*)&pb;
        *(uint2*)&A[(size_t)n0 * HID + fq] = pk;
        ao0.x += bb.x; ao0.y += bb.y; ao0.z += bb.z; ao0.w += bb.w;
        *(float4*)&C[(size_t)n0 * HID + fq] = ao0;
    }
    if (n1 < N) {
        __half2 pa = __floats2half2_rn(ar1.x, ar1.y);
        __half2 pb = __floats2half2_rn(ar1.z, ar1.w);
        uint2 pk; pk.x = *(unsigned*)&pa; pk.y = *(unsigned*)&pb;
        *(uint2*)&A[(size_t)n1 * HID + fq] = pk;
        ao1.x += bb.x; ao1.y += bb.y; ao1.z += bb.z; ao1.w += bb.w;
        *(float4*)&C[(size_t)n1 * HID + fq] = ao1;
    }
}

// ---------- bucket_scan: per-bucket exclusive scan of cbb rows -> btot ----------
__global__ __launch_bounds__(256) void bucket_scan(
    int* __restrict__ cbb, int* __restrict__ btot, int NBLK)
{
    __shared__ int sc[256];
    size_t row = (size_t)blockIdx.x * NBLK;
    int t = threadIdx.x;
    int base = t * 4;
    int v[4]; int s = 0;
    #pragma unroll
    for (int j = 0; j < 4; ++j) { v[j] = (base + j < NBLK) ? cbb[row + base + j] : 0; s += v[j]; }
    sc[t] = s;
    __syncthreads();
    int acc = s;
    for (int off = 1; off < 256; off <<= 1) {
        int add = (t >= off) ? sc[t - off] : 0;
        __syncthreads();
        acc += add;
        sc[t] = acc;
        __syncthreads();
    }
    int run = acc - s;
    #pragma unroll
    for (int j = 0; j < 4; ++j) {
        if (base + j < NBLK) cbb[row + base + j] = run;
        run += v[j];
    }
    if (t == 255) btot[blockIdx.x] = acc;
}

// partition: 4096 edges/block, 512 threads; scans btot in LDS itself.
__global__ __launch_bounds__(512) void partB(
    const int* __restrict__ src, const int* __restrict__ dst,
    const float* __restrict__ ew, const int* __restrict__ cbb,
    const int* __restrict__ btot, int* __restrict__ bbase,
    int2* __restrict__ stg8, int E, int K, int NBLK)
{
    __shared__ int2 pay[EPB];               // 32 KB
    __shared__ unsigned short bid[EPB];     // 8 KB
    __shared__ int h[KMAX2];
    __shared__ int lofs[KMAX2];
    __shared__ int gb[KMAX2];
    __shared__ int sbase[KMAX2];
    __shared__ int sc[512];
    int tid = threadIdx.x;
    for (int i = tid; i < K; i += 512) h[i] = 0;

    // ---- LDS scan of btot -> sbase (exclusive); block 0 publishes globally ----
    int bv = (tid < K) ? btot[tid] : 0;
    sc[tid] = bv;
    __syncthreads();
    int bacc = bv;
    for (int off = 1; off < 512; off <<= 1) {
        int add = (tid >= off) ? sc[tid - off] : 0;
        __syncthreads();
        bacc += add;
        sc[tid] = bacc;
        __syncthreads();
    }
    if (tid < K) sbase[tid] = bacc - bv;
    if (blockIdx.x == 0) {
        if (tid < K) bbase[tid] = bacc - bv;
        if (tid == K - 1) bbase[K] = bacc;     // = E
    }
    __syncthreads();

    int base = blockIdx.x * EPB;
    int es[8], ds[8]; float wsr[8];
    #pragma unroll
    for (int k = 0; k < 8; ++k) {
        int e = base + k * 512 + tid;
        if (e < E) {
            es[k] = src[e]; ds[k] = dst[e]; wsr[k] = ew[e];
            atomicAdd(&h[ds[k] >> NB_SHIFT], 1);
        } else ds[k] = -1;
    }
    __syncthreads();

    // block-scan hist: thread t owns bucket t (K <= 512)
    int v0 = (tid < K) ? h[tid] : 0;
    sc[tid] = v0;
    __syncthreads();
    int acc = v0;
    for (int off = 1; off < 512; off <<= 1) {
        int add = (tid >= off) ? sc[tid - off] : 0;
        __syncthreads();
        acc += add;
        sc[tid] = acc;
        __syncthreads();
    }
    if (tid < K) lofs[tid] = acc - v0;
    __syncthreads();

    for (int b = tid; b < K; b += 512) {
        gb[b] = sbase[b] + cbb[(size_t)b * NBLK + blockIdx.x];
        h[b] = lofs[b];
    }
    __syncthreads();

    #pragma unroll
    for (int k = 0; k < 8; ++k) {
        if (ds[k] >= 0) {
            int b = ds[k] >> NB_SHIFT;
            int dloc = ds[k] & (NB_NODES - 1);
            int slot = atomicAdd(&h[b], 1);
            pay[slot] = make_int2(es[k] | (dloc << 17), __float_as_int(wsr[k]));
            bid[slot] = (unsigned short)b;
        }
    }
    __syncthreads();

    int tot = E - base; if (tot > EPB) tot = EPB;
    for (int i = tid; i < tot; i += 512) {
        int b = bid[i];
        stg8[gb[b] + i - lofs[b]] = pay[i];
    }
}

// per bucket: counting-sort edges by dst node, LDS-staged single-pass.
// perm payload: {src, weight as DUPLICATED half2} -> zero converts in csr_agg.
__global__ __launch_bounds__(512) void partC2(
    const int2* __restrict__ stg8, const int* __restrict__ bbase,
    int* __restrict__ rowptr, int2* __restrict__ perm, int N, int K)
{
    __shared__ int2 pe[PCAP];          // 47 KB edge staging
    __shared__ int hcnt[NB_NODES];
    __shared__ int hinc[NB_NODES];
    int b = blockIdx.x;
    int n0 = b << NB_SHIFT;
    int nTop = n0 + NB_NODES; if (nTop > N) nTop = N;
    int nloc = nTop - n0;
    int tid = threadIdx.x;
    if (tid < NB_NODES) hcnt[tid] = 0;
    int lo = bbase[b], hi = bbase[b + 1];
    int sz = hi - lo;
    bool fit = (sz <= PCAP);
    if (fit) {
        for (int i = tid; i < sz; i += 512) pe[i] = stg8[lo + i];
    }
    __syncthreads();
    if (fit) {
        for (int i = tid; i < sz; i += 512)
            atomicAdd(&hcnt[pe[i].x >> 17], 1);
    } else {
        for (int e = lo + tid; e < hi; e += 512)
            atomicAdd(&hcnt[stg8[e].x >> 17], 1);
    }
    __syncthreads();
    if (tid < NB_NODES) hinc[tid] = hcnt[tid];
    __syncthreads();
    for (int off = 1; off < NB_NODES; off <<= 1) {
        int v = (tid < NB_NODES && tid >= off) ? hinc[tid - off] : 0;
        __syncthreads();
        if (tid < NB_NODES) hinc[tid] += v;
        __syncthreads();
    }
    if (tid < nloc) {
        int excl = hinc[tid] - hcnt[tid];
        rowptr[n0 + tid] = lo + excl;
        hcnt[tid] = excl;               // reuse as cursor
    }
    if (b == K - 1 && tid == 0) rowptr[N] = hi;
    __syncthreads();
    if (fit) {
        for (int i = tid; i < sz; i += 512) {
            int2 p = pe[i];
            __half hw = __float2half(__int_as_float(p.y));
            unsigned hb = *(unsigned short*)&hw;
            int pos = lo + atomicAdd(&hcnt[p.x >> 17], 1);
            perm[pos] = make_int2(p.x & 0x1FFFF, (int)((hb << 16) | hb));
        }
    } else {
        for (int e = lo + tid; e < hi; e += 512) {
            int2 p = stg8[e];
            __half hw = __float2half(__int_as_float(p.y));
            unsigned hb = *(unsigned short*)&hw;
            int pos = lo + atomicAdd(&hcnt[p.x >> 17], 1);
            perm[pos] = make_int2(p.x & 0x1FFFF, (int)((hb << 16) | hb));
        }
    }
}

// ---------- gather-side aggregation: 4 lanes per node, packed-fp16 FMA ----------
// lane q owns features [8q, 8q+8) via one uint4 load per edge; weight arrives
// pre-packed as half2 in perm.y -> inner loop is loads + v_pk_fma_f16 only.
__global__ __launch_bounds__(256) void csr_agg(
    const int* __restrict__ rowptr, const int2* __restrict__ perm,
    const __half* __restrict__ A, float* __restrict__ out, int N)
{
    int gid = blockIdx.x * 256 + threadIdx.x;
    int n = gid >> 2;            // 4 threads per node
    if (n >= N) return;
    int q = threadIdx.x & 3;     // uint4 column within 32-half row
    int e0 = rowptr[n], e1 = rowptr[n + 1];
    const uint4* A4 = (const uint4*)A;   // row stride = 4 uint4
    __half2 z = __floats2half2_rn(0.f, 0.f);
    __half2 acc0[4] = {z, z, z, z};
    __half2 acc1[4] = {z, z, z, z};
    int e = e0;
    for (; e + 1 < e1; e += 2) {
        int2 p0 = perm[e];
        int2 p1 = perm[e + 1];
        uint4 r0 = A4[(size_t)p0.x * 4 + q];
        uint4 r1 = A4[(size_t)p1.x * 4 + q];
        __half2 w0 = *(__half2*)&p0.y;
        __half2 w1 = *(__half2*)&p1.y;
        acc0[0] = __hfma2(*(__half2*)&r0.x, w0, acc0[0]);
        acc0[1] = __hfma2(*(__half2*)&r0.y, w0, acc0[1]);
        acc0[2] = __hfma2(*(__half2*)&r0.z, w0, acc0[2]);
        acc0[3] = __hfma2(*(__half2*)&r0.w, w0, acc0[3]);
        acc1[0] = __hfma2(*(__half2*)&r1.x, w1, acc1[0]);
        acc1[1] = __hfma2(*(__half2*)&r1.y, w1, acc1[1]);
        acc1[2] = __hfma2(*(__half2*)&r1.z, w1, acc1[2]);
        acc1[3] = __hfma2(*(__half2*)&r1.w, w1, acc1[3]);
    }
    if (e < e1) {
        int2 p = perm[e];
        uint4 r = A4[(size_t)p.x * 4 + q];
        __half2 w = *(__half2*)&p.y;
        acc0[0] = __hfma2(*(__half2*)&r.x, w, acc0[0]);
        acc0[1] = __hfma2(*(__half2*)&r.y, w, acc0[1]);
        acc0[2] = __hfma2(*(__half2*)&r.z, w, acc0[2]);
        acc0[3] = __hfma2(*(__half2*)&r.w, w, acc0[3]);
    }
    // convert to fp32 and combine the two accumulator sets (fp32 add)
    float2 f0 = __half22float2(acc0[0]);
    float2 g0 = __half22float2(acc1[0]);
    float2 f1 = __half22float2(acc0[1]);
    float2 g1 = __half22float2(acc1[1]);
    float2 f2 = __half22float2(acc0[2]);
    float2 g2 = __half22float2(acc1[2]);
    float2 f3 = __half22float2(acc0[3]);
    float2 g3 = __half22float2(acc1[3]);
    float4* O4 = (float4*)out;
    size_t oi = (size_t)n * 8 + q * 2;
    float4 o = O4[oi];
    o.x += f0.x + g0.x; o.y += f0.y + g0.y;
    o.z += f1.x + g1.x; o.w += f1.y + g1.y;
    O4[oi] = o;
    float4 p = O4[oi + 1];
    p.x += f2.x + g2.x; p.y += f2.y + g2.y;
    p.z += f3.x + g3.x; p.w += f3.y + g3.y;
    O4[oi + 1] = p;
}

// ---------- fused pool + MLP: one block per graph, batch sorted ----------
__global__ __launch_bounds__(256) void pool_mlp(
    const float* __restrict__ C, const int* __restrict__ batch, int N,
    const float* __restrict__ W1, const float* __restrict__ b1,
    const float* __restrict__ W2, const float* __restrict__ b2,
    const float* __restrict__ W3, const float* __restrict__ b3,
    float* __restrict__ out)
{
    int g = blockIdx.x;
    int tid = threadIdx.x;
    int lo, hi;
    {
        int l = 0, r = N;
        while (l < r) { int m = (l + r) >> 1; if (batch[m] < g) l = m + 1; else r = m; }
        lo = l;
        r = N;
        while (l < r) { int m = (l + r) >> 1; if (batch[m] < g + 1) l = m + 1; else r = m; }
        hi = l;
    }
    __shared__ float ssum[8][32];
    __shared__ float gvec[32];
    __shared__ float h1v[32];
    __shared__ float h2v[16];
    int f = tid & 31, seg = tid >> 5;
    float acc = 0.f;
    for (int n = lo + seg; n < hi; n += 8) {
        float v = C[(size_t)n * HID + f];
        acc += v > 0.f ? v : 0.f;
    }
    ssum[seg][f] = acc;
    __syncthreads();
    if (tid < 32) {
        float s = 0.f;
        #pragma unroll
        for (int k = 0; k < 8; ++k) s += ssum[k][tid];
        float c = (float)(hi - lo); c = c > 1.f ? c : 1.f;
        gvec[tid] = s / c;
    }
    __syncthreads();
    if (tid < 32) {
        float a = b1[tid];
        #pragma unroll
        for (int k = 0; k < 32; ++k) a = fmaf(gvec[k], W1[k * 32 + tid], a);
        h1v[tid] = a > 0.f ? a : 0.f;
    }
    __syncthreads();
    if (tid < 16) {
        float a = b2[tid];
        #pragma unroll
        for (int k = 0; k < 32; ++k) a = fmaf(h1v[k], W2[k * 16 + tid], a);
        h2v[tid] = a > 0.f ? a : 0.f;
    }
    __syncthreads();
    if (tid == 0) {
        float o = b3[0];
        #pragma unroll
        for (int k = 0; k < 16; ++k) o = fmaf(h2v[k], W3[k], o);
        out[g] = o;
    }
}

extern "C" void kernel_launch(void* const* d_in, const int* in_sizes, int n_in,
                              void* d_out, int out_size, void* d_ws, size_t ws_size,
                              hipStream_t stream) {
    const float* x     = (const float*)d_in[0];
    const int*   ei    = (const int*)d_in[1];
    const float* ew    = (const float*)d_in[2];
    const int*   batch = (const int*)d_in[3];
    const float* c1rw  = (const float*)d_in[4];
    const float* c1rb  = (const float*)d_in[5];
    const float* c1ow  = (const float*)d_in[6];
    const float* c2rw  = (const float*)d_in[7];
    const float* c2rb  = (const float*)d_in[8];
    const float* c2ow  = (const float*)d_in[9];
    const float* l1w   = (const float*)d_in[10];
    const float* l1b   = (const float*)d_in[11];
    const float* l2w   = (const float*)d_in[12];
    const float* l2b   = (const float*)d_in[13];
    const float* lw    = (const float*)d_in[14];
    const float* lb    = (const float*)d_in[15];

    int N = in_sizes[0] / FIN;      // 100000
    int E = in_sizes[2];            // 1600000
    const int* src = ei;
    const int* dst = ei + E;
    int K    = (N + NB_NODES - 1) >> NB_SHIFT;   // 391 buckets (256 nodes)
    int NBLK = (E + EPB - 1) / EPB;              // 391 edge blocks (4096 each)

    // ---- workspace layout (no aliasing: lin64 runs concurrently with build) ----
    char* ws = (char*)d_ws;
    size_t off = 0;
    auto alloc = [&](size_t nbytes) { void* p = ws + off; off += (nbytes + 255) & ~size_t(255); return p; };
    __half* A      = (__half*)alloc((size_t)N * HID * 2);        // 6.4 MB (fp16)
    float*  BC     = (float*) alloc((size_t)N * HID * 4);        // 12.8 MB
    int2*   perm   = (int2*)  alloc((size_t)E * 8);              // 12.8 MB
    int2*   stg8   = (int2*)  alloc((size_t)E * 8);              // 12.8 MB
    int*    cbb    = (int*)   alloc((size_t)K * NBLK * 4);       // 0.61 MB
    int*    rowptr = (int*)   alloc((size_t)(N + 1) * 4);
    int*    btot   = (int*)   alloc((size_t)KMAX2 * 4);
    int*    bbase  = (int*)   alloc((size_t)(KMAX2 + 1) * 4);

    int nb_node = (N + NT - 1) / NT;
    int nb_agg  = (int)(((long long)N * 4 + 255) / 256);   // 4 threads per node

    // fused: histogram (NBLK blocks) || conv1 linear (nb_node blocks)
    hist_lin64<<<NBLK + nb_node, 256, 0, stream>>>(
        dst, cbb, E, K, NBLK, x, c1rw, c1ow, c1rb, A, BC, N);
    // partition build: scan, then partB (absorbs btot scan, publishes bbase)
    bucket_scan<<<K, 256, 0, stream>>>(cbb, btot, NBLK);
    partB<<<NBLK, 512, 0, stream>>>(src, dst, ew, cbb, btot, bbase, stg8, E, K, NBLK);
    partC2<<<K, 512, 0, stream>>>(stg8, bbase, rowptr, perm, N, K);

    // conv1 aggregation
    csr_agg<<<nb_agg, 256, 0, stream>>>(rowptr, perm, A, BC, N);
    // conv2 (relu fused into node_lin32 load; A overwritten with layer-2 rel-proj)
    node_lin32<<<nb_node, 256, 0, stream>>>(BC, c2rw, c2ow, c2rb, A, BC, N);
    csr_agg<<<nb_agg, 256, 0, stream>>>(rowptr, perm, A, BC, N);
    // fused pool + MLP
    pool_mlp<<<NGRAPH, 256, 0, stream>>>(BC, batch, N, l1w, l1b, l2w, l2b, lw, lb,
                                         (float*)d_out);
}